// Round 1
// baseline (2272.087 us; speedup 1.0000x reference)
//
#include <hip/hip_runtime.h>

#define NN 30000
#define EE 240000
#define ET 270000          // E + N self loops
#define GG 1000
#define NH 10
#define FF 78
#define HID 780
#define NEG_SLOPE 0.2f

// ---------------------------------------------------------------- init
__global__ void init_kernel(int* __restrict__ cnt, int* __restrict__ fill,
                            int* __restrict__ lo, int* __restrict__ hi) {
  int i = blockIdx.x * blockDim.x + threadIdx.x;
  if (i < NN) { cnt[i] = 0; fill[i] = 0; }
  if (i < GG) { lo[i] = NN; hi[i] = 0; }
}

// ---------------------------------------------------------------- sgemm
// C[M,N] = A[M,K] @ B[K,N] (+bias) (relu), all row-major fp32
#define BM 64
#define BN 64
#define BK 16
__global__ __launch_bounds__(256) void sgemm_kernel(
    int M, int N, int K,
    const float* __restrict__ A, const float* __restrict__ B,
    const float* __restrict__ bias, float* __restrict__ C, int relu) {
  __shared__ float As[BK][BM + 1];
  __shared__ float Bs[BK][BN];
  int tid = threadIdx.x;
  int tx = tid & 15, ty = tid >> 4;
  int row0 = blockIdx.y * BM, col0 = blockIdx.x * BN;
  float acc[4][4] = {};
  for (int k0 = 0; k0 < K; k0 += BK) {
    for (int li = tid; li < BM * BK; li += 256) {
      int m = li >> 4, k = li & 15;
      int gm = row0 + m, gk = k0 + k;
      As[k][m] = (gm < M && gk < K) ? A[(size_t)gm * K + gk] : 0.f;
    }
    for (int li = tid; li < BK * BN; li += 256) {
      int k = li >> 6, n = li & 63;
      int gk = k0 + k, gn = col0 + n;
      Bs[k][n] = (gk < K && gn < N) ? B[(size_t)gk * N + gn] : 0.f;
    }
    __syncthreads();
    for (int k = 0; k < BK; k++) {
      float ra[4], rb[4];
      for (int m = 0; m < 4; m++) ra[m] = As[k][ty * 4 + m];
      for (int n = 0; n < 4; n++) rb[n] = Bs[k][tx * 4 + n];
      for (int m = 0; m < 4; m++)
        for (int n = 0; n < 4; n++)
          acc[m][n] += ra[m] * rb[n];
    }
    __syncthreads();
  }
  for (int m = 0; m < 4; m++) {
    int gm = row0 + ty * 4 + m;
    if (gm >= M) continue;
    for (int n = 0; n < 4; n++) {
      int gn = col0 + tx * 4 + n;
      if (gn >= N) continue;
      float v = acc[m][n];
      if (bias) v += bias[gn];
      if (relu) v = fmaxf(v, 0.f);
      C[(size_t)gm * N + gn] = v;
    }
  }
}

// ---------------------------------------------------------------- att dots
// a_src[n,h] = sum_f h[n,h*F+f]*att_src[h*F+f]; same for dst
__global__ __launch_bounds__(128) void att_kernel(
    const float* __restrict__ hbuf, const float* __restrict__ att_src,
    const float* __restrict__ att_dst, float* __restrict__ a_src,
    float* __restrict__ a_dst) {
  __shared__ float row[HID];
  int n = blockIdx.x;
  for (int i = threadIdx.x; i < HID; i += 128) row[i] = hbuf[(size_t)n * HID + i];
  __syncthreads();
  int t = threadIdx.x;
  if (t < 2 * NH) {
    int hh = t % NH;
    const float* att = (t < NH) ? att_src : att_dst;
    float s = 0.f;
    for (int f = 0; f < FF; f++) s += row[hh * FF + f] * att[hh * FF + f];
    if (t < NH) a_src[n * NH + hh] = s;
    else        a_dst[n * NH + hh] = s;
  }
}

// ---------------------------------------------------------------- CSR build
__device__ __forceinline__ void edge_sd(const int* __restrict__ ei, int t,
                                        int& s, int& d) {
  if (t < EE) { s = ei[t]; d = ei[EE + t]; }
  else        { s = t - EE; d = t - EE; }
}

__global__ void count_kernel(const int* __restrict__ ei, int* __restrict__ cnt) {
  int t = blockIdx.x * blockDim.x + threadIdx.x;
  if (t < ET) { int s, d; edge_sd(ei, t, s, d); atomicAdd(&cnt[d], 1); }
}

__global__ __launch_bounds__(1024) void scan_kernel(const int* __restrict__ cnt,
                                                    int* __restrict__ row_ptr) {
  __shared__ int buf[1024];
  __shared__ int carry;
  if (threadIdx.x == 0) carry = 0;
  __syncthreads();
  for (int base = 0; base < NN; base += 1024) {
    int i = base + threadIdx.x;
    int v = (i < NN) ? cnt[i] : 0;
    buf[threadIdx.x] = v;
    __syncthreads();
    for (int off = 1; off < 1024; off <<= 1) {
      int t = (threadIdx.x >= off) ? buf[threadIdx.x - off] : 0;
      __syncthreads();
      buf[threadIdx.x] += t;
      __syncthreads();
    }
    if (i < NN) row_ptr[i] = carry + buf[threadIdx.x] - v;  // exclusive
    __syncthreads();
    if (threadIdx.x == 1023) carry += buf[1023];
    __syncthreads();
  }
  if (threadIdx.x == 0) row_ptr[NN] = carry;
}

__global__ void scatter_kernel(const int* __restrict__ ei,
                               const int* __restrict__ row_ptr,
                               int* __restrict__ fill,
                               int* __restrict__ col_src) {
  int t = blockIdx.x * blockDim.x + threadIdx.x;
  if (t < ET) {
    int s, d; edge_sd(ei, t, s, d);
    int pos = row_ptr[d] + atomicAdd(&fill[d], 1);
    col_src[pos] = s;
  }
}

__global__ void dinv_kernel(const int* __restrict__ row_ptr,
                            float* __restrict__ dinv) {
  int i = blockIdx.x * blockDim.x + threadIdx.x;
  if (i < NN) {
    int d = row_ptr[i + 1] - row_ptr[i];
    dinv[i] = rsqrtf((float)max(d, 1));
  }
}

// ---------------------------------------------------------------- GAT aggregate
#define AGG_BLOCK 832    // 13 waves; threads 0..779 own one feature each
#define CHUNK 32
__global__ __launch_bounds__(AGG_BLOCK) void gat_aggr_kernel(
    const int* __restrict__ row_ptr, const int* __restrict__ col_src,
    const float* __restrict__ a_src, const float* __restrict__ a_dst,
    const float* __restrict__ hbuf, const float* __restrict__ b_gat,
    float* __restrict__ out) {
  int d = blockIdx.x;
  int beg = row_ptr[d], end = row_ptr[d + 1];
  int tid = threadIdx.x;
  __shared__ float m_s[NH], sum_s[NH];
  __shared__ float alpha_s[CHUNK * NH];
  __shared__ int src_s[CHUNK];
  // phase 1: per-head running max then exp-sum (10 threads, deg ~9 serial)
  if (tid < NH) {
    float ad = a_dst[d * NH + tid];
    float m = -1e30f;
    for (int e = beg; e < end; e++) {
      float v = a_src[col_src[e] * NH + tid] + ad;
      v = (v > 0.f) ? v : v * NEG_SLOPE;
      m = fmaxf(m, v);
    }
    float ssum = 0.f;
    for (int e = beg; e < end; e++) {
      float v = a_src[col_src[e] * NH + tid] + ad;
      v = (v > 0.f) ? v : v * NEG_SLOPE;
      ssum += __expf(v - m);
    }
    m_s[tid] = m;
    sum_s[tid] = ssum;
  }
  __syncthreads();
  int f = tid;
  int hh = (f < HID) ? (f / FF) : 0;
  float acc = 0.f;
  for (int c = beg; c < end; c += CHUNK) {
    int ce = min(CHUNK, end - c);
    if (tid < ce * NH) {
      int j = tid / NH, h = tid % NH;
      int s = col_src[c + j];
      float v = a_src[s * NH + h] + a_dst[d * NH + h];
      v = (v > 0.f) ? v : v * NEG_SLOPE;
      alpha_s[j * NH + h] = __expf(v - m_s[h]) / sum_s[h];
      if (h == 0) src_s[j] = s;
    }
    __syncthreads();
    if (f < HID) {
      for (int j = 0; j < ce; j++)
        acc += hbuf[(size_t)src_s[j] * HID + f] * alpha_s[j * NH + hh];
    }
    __syncthreads();
  }
  if (f < HID)
    out[(size_t)d * HID + f] = fmaxf(acc + b_gat[f], 0.f);
}

// ---------------------------------------------------------------- GCN aggregate
__global__ __launch_bounds__(AGG_BLOCK) void gcn_aggr_kernel(
    const int* __restrict__ row_ptr, const int* __restrict__ col_src,
    const float* __restrict__ dinv, const float* __restrict__ h2,
    const float* __restrict__ b_gcn, float* __restrict__ out2) {
  int d = blockIdx.x;
  int beg = row_ptr[d], end = row_ptr[d + 1];
  int tid = threadIdx.x;
  float dv = dinv[d];
  __shared__ float w_s[CHUNK];
  __shared__ int src_s[CHUNK];
  float acc = 0.f;
  for (int c = beg; c < end; c += CHUNK) {
    int ce = min(CHUNK, end - c);
    if (tid < ce) {
      int s = col_src[c + tid];
      src_s[tid] = s;
      w_s[tid] = dinv[s] * dv;
    }
    __syncthreads();
    if (tid < HID) {
      for (int j = 0; j < ce; j++)
        acc += h2[(size_t)src_s[j] * HID + tid] * w_s[j];
    }
    __syncthreads();
  }
  if (tid < HID)
    out2[(size_t)d * HID + tid] = fmaxf(acc + b_gcn[tid], 0.f);
}

// ---------------------------------------------------------------- pooling
__global__ void bounds_kernel(const int* __restrict__ batch,
                              int* __restrict__ lo, int* __restrict__ hi) {
  int i = blockIdx.x * blockDim.x + threadIdx.x;
  if (i < NN) {
    int g = batch[i];
    atomicMin(&lo[g], i);
    atomicMax(&hi[g], i + 1);
  }
}

__global__ __launch_bounds__(AGG_BLOCK) void pool_kernel(
    const float* __restrict__ out2, const int* __restrict__ lo,
    const int* __restrict__ hi, float* __restrict__ pooled) {
  int g = blockIdx.x;
  int l = lo[g], h = hi[g];
  int f = threadIdx.x;
  if (f >= HID) return;
  float s = 0.f, mx = -1e30f;
  for (int n = l; n < h; n++) {
    float v = out2[(size_t)n * HID + f];
    s += v;
    mx = fmaxf(mx, v);
  }
  if (h <= l) { s = 0.f; mx = 0.f; }
  else s = s / (float)(h - l);
  pooled[(size_t)g * (2 * HID) + f] = s;
  pooled[(size_t)g * (2 * HID) + HID + f] = mx;
}

// ---------------------------------------------------------------- launch
extern "C" void kernel_launch(void* const* d_in, const int* in_sizes, int n_in,
                              void* d_out, int out_size, void* d_ws,
                              size_t ws_size, hipStream_t stream) {
  const float* x        = (const float*)d_in[0];
  const int*   edge_idx = (const int*)d_in[1];
  const int*   batch    = (const int*)d_in[2];
  const float* W_gat    = (const float*)d_in[3];
  const float* att_src  = (const float*)d_in[4];
  const float* att_dst  = (const float*)d_in[5];
  const float* b_gat    = (const float*)d_in[6];
  const float* W_gcn    = (const float*)d_in[7];
  const float* b_gcn    = (const float*)d_in[8];
  const float* W1       = (const float*)d_in[9];
  const float* b1       = (const float*)d_in[10];
  const float* W2       = (const float*)d_in[11];
  const float* b2       = (const float*)d_in[12];
  float* out = (float*)d_out;
  (void)in_sizes; (void)n_in; (void)out_size; (void)ws_size;

  char* ws = (char*)d_ws;
  size_t off = 0;
  auto alloc = [&](size_t bytes) -> void* {
    void* p = ws + off;
    off += (bytes + 255) & ~(size_t)255;
    return p;
  };
  float* bufA    = (float*)alloc((size_t)NN * HID * 4);  // h, then h2
  float* bufB    = (float*)alloc((size_t)NN * HID * 4);  // out_gat, then out2
  float* a_src_b = (float*)alloc((size_t)NN * NH * 4);
  float* a_dst_b = (float*)alloc((size_t)NN * NH * 4);
  int*   cnt     = (int*)alloc((size_t)NN * 4);
  int*   fill    = (int*)alloc((size_t)NN * 4);
  int*   row_ptr = (int*)alloc((size_t)(NN + 1) * 4);
  int*   col_src = (int*)alloc((size_t)ET * 4);
  int*   lo      = (int*)alloc((size_t)GG * 4);
  int*   hi      = (int*)alloc((size_t)GG * 4);
  float* dinv    = (float*)alloc((size_t)NN * 4);
  float* pooled  = (float*)alloc((size_t)GG * 2 * HID * 4);
  float* hidfc   = (float*)alloc((size_t)GG * 1500 * 4);

  init_kernel<<<(NN + 255) / 256, 256, 0, stream>>>(cnt, fill, lo, hi);

  {  // h = x @ W_gat
    dim3 grid((HID + BN - 1) / BN, (NN + BM - 1) / BM);
    sgemm_kernel<<<grid, 256, 0, stream>>>(NN, HID, FF, x, W_gat, nullptr, bufA, 0);
  }
  att_kernel<<<NN, 128, 0, stream>>>(bufA, att_src, att_dst, a_src_b, a_dst_b);

  count_kernel<<<(ET + 255) / 256, 256, 0, stream>>>(edge_idx, cnt);
  scan_kernel<<<1, 1024, 0, stream>>>(cnt, row_ptr);
  scatter_kernel<<<(ET + 255) / 256, 256, 0, stream>>>(edge_idx, row_ptr, fill, col_src);
  dinv_kernel<<<(NN + 255) / 256, 256, 0, stream>>>(row_ptr, dinv);

  gat_aggr_kernel<<<NN, AGG_BLOCK, 0, stream>>>(row_ptr, col_src, a_src_b,
                                                a_dst_b, bufA, b_gat, bufB);
  {  // h2 = out_gat @ W_gcn
    dim3 grid((HID + BN - 1) / BN, (NN + BM - 1) / BM);
    sgemm_kernel<<<grid, 256, 0, stream>>>(NN, HID, HID, bufB, W_gcn, nullptr, bufA, 0);
  }
  gcn_aggr_kernel<<<NN, AGG_BLOCK, 0, stream>>>(row_ptr, col_src, dinv, bufA,
                                                b_gcn, bufB);

  bounds_kernel<<<(NN + 255) / 256, 256, 0, stream>>>(batch, lo, hi);
  pool_kernel<<<GG, AGG_BLOCK, 0, stream>>>(bufB, lo, hi, pooled);

  {  // hidfc = relu(pooled @ W1 + b1)
    dim3 grid((1500 + BN - 1) / BN, (GG + BM - 1) / BM);
    sgemm_kernel<<<grid, 256, 0, stream>>>(GG, 1500, 2 * HID, pooled, W1, b1, hidfc, 1);
  }
  {  // out = hidfc @ W2 + b2
    dim3 grid((128 + BN - 1) / BN, (GG + BM - 1) / BM);
    sgemm_kernel<<<grid, 256, 0, stream>>>(GG, 128, 1500, hidfc, W2, b2, out, 0);
  }
}

// Round 2
// 1666.497 us; speedup vs baseline: 1.3634x; 1.3634x over previous
//
#include <hip/hip_runtime.h>

#define NN 30000
#define EE 240000
#define ET 270000          // E + N self loops
#define GG 1000
#define NH 10
#define FF 78
#define HID 780
#define NEG_SLOPE 0.2f

// MFMA GEMM geometry (GCN layer: [NN,HID] @ [HID,HID])
#define KP 800             // HID padded to multiple of 32
#define NP 896             // HID padded to multiple of 128
#define MT 128
#define NT 128
#define KB 32

typedef __bf16 bf16_8 __attribute__((ext_vector_type(8)));
typedef float f32x4 __attribute__((ext_vector_type(4)));

__device__ __forceinline__ void async_copy16(const void* g, void* l) {
  __builtin_amdgcn_global_load_lds(
      (const __attribute__((address_space(1))) void*)g,
      (__attribute__((address_space(3))) void*)l, 16, 0, 0);
}

// ---------------------------------------------------------------- init
__global__ void init_kernel(int* __restrict__ cnt, int* __restrict__ fill,
                            int* __restrict__ lo, int* __restrict__ hi) {
  int i = blockIdx.x * blockDim.x + threadIdx.x;
  if (i < NN) { cnt[i] = 0; fill[i] = 0; }
  if (i < GG) { lo[i] = NN; hi[i] = 0; }
}

// ---------------------------------------------------------------- sgemm (fp32)
// C[M,N] = A[M,K] @ B[K,N] (+bias) (relu), all row-major fp32
#define BM 64
#define BN 64
#define BK 16
__global__ __launch_bounds__(256) void sgemm_kernel(
    int M, int N, int K,
    const float* __restrict__ A, const float* __restrict__ B,
    const float* __restrict__ bias, float* __restrict__ C, int relu) {
  __shared__ float As[BK][BM + 1];
  __shared__ float Bs[BK][BN];
  int tid = threadIdx.x;
  int tx = tid & 15, ty = tid >> 4;
  int row0 = blockIdx.y * BM, col0 = blockIdx.x * BN;
  float acc[4][4] = {};
  for (int k0 = 0; k0 < K; k0 += BK) {
    for (int li = tid; li < BM * BK; li += 256) {
      int m = li >> 4, k = li & 15;
      int gm = row0 + m, gk = k0 + k;
      As[k][m] = (gm < M && gk < K) ? A[(size_t)gm * K + gk] : 0.f;
    }
    for (int li = tid; li < BK * BN; li += 256) {
      int k = li >> 6, n = li & 63;
      int gk = k0 + k, gn = col0 + n;
      Bs[k][n] = (gk < K && gn < N) ? B[(size_t)gk * N + gn] : 0.f;
    }
    __syncthreads();
    for (int k = 0; k < BK; k++) {
      float ra[4], rb[4];
      for (int m = 0; m < 4; m++) ra[m] = As[k][ty * 4 + m];
      for (int n = 0; n < 4; n++) rb[n] = Bs[k][tx * 4 + n];
      for (int m = 0; m < 4; m++)
        for (int n = 0; n < 4; n++)
          acc[m][n] += ra[m] * rb[n];
    }
    __syncthreads();
  }
  for (int m = 0; m < 4; m++) {
    int gm = row0 + ty * 4 + m;
    if (gm >= M) continue;
    for (int n = 0; n < 4; n++) {
      int gn = col0 + tx * 4 + n;
      if (gn >= N) continue;
      float v = acc[m][n];
      if (bias) v += bias[gn];
      if (relu) v = fmaxf(v, 0.f);
      C[(size_t)gm * N + gn] = v;
    }
  }
}

// ---------------------------------------------------------------- bf16 MFMA GEMM
// C[NN,HID] (fp32) = A[NN,KP] (bf16, zero-padded K) @ BT[NP,KP]^T (bf16)
__global__ __launch_bounds__(256) void gemm_mfma_kernel(
    const __bf16* __restrict__ A, const __bf16* __restrict__ BT,
    float* __restrict__ C) {
  __shared__ __bf16 As[MT][KB];   // 8 KB
  __shared__ __bf16 Bs[NT][KB];   // 8 KB
  int tid = threadIdx.x;
  int lane = tid & 63;
  int wave = tid >> 6;
  int row0 = blockIdx.y * MT, col0 = blockIdx.x * NT;
  int wm = (wave & 1) * 64;   // wave's 64x64 sub-tile
  int wn = (wave >> 1) * 64;
  int l15 = lane & 15;
  int quad = lane >> 4;
  f32x4 acc[4][4] = {};

  for (int k0 = 0; k0 < KP; k0 += KB) {
    // stage A tile: 128 rows x 32 k = 8 KB = 512 chunks of 16B
    for (int t = 0; t < 2; t++) {
      int c = tid + t * 256;
      int r = c >> 2, kc = c & 3;
      const __bf16* g = A + (size_t)(row0 + r) * KP + k0 + kc * 8;
      char* l = (char*)&As[0][0] + (size_t)((tid & ~63) + t * 256) * 16;
      async_copy16(g, l);
    }
    // stage B tile (transposed weight): 128 n-rows x 32 k
    for (int t = 0; t < 2; t++) {
      int c = tid + t * 256;
      int r = c >> 2, kc = c & 3;
      const __bf16* g = BT + (size_t)(col0 + r) * KP + k0 + kc * 8;
      char* l = (char*)&Bs[0][0] + (size_t)((tid & ~63) + t * 256) * 16;
      async_copy16(g, l);
    }
    __syncthreads();

    bf16_8 af[4], bfv[4];
    for (int mt = 0; mt < 4; mt++)
      af[mt] = *(const bf16_8*)&As[wm + mt * 16 + l15][quad * 8];
    for (int nt = 0; nt < 4; nt++)
      bfv[nt] = *(const bf16_8*)&Bs[wn + nt * 16 + l15][quad * 8];
    for (int mt = 0; mt < 4; mt++)
      for (int nt = 0; nt < 4; nt++)
        acc[mt][nt] = __builtin_amdgcn_mfma_f32_16x16x32_bf16(
            af[mt], bfv[nt], acc[mt][nt], 0, 0, 0);
    __syncthreads();
  }

  // epilogue: C/D layout col=lane&15, row=quad*4+reg
  for (int nt = 0; nt < 4; nt++) {
    int col = col0 + wn + nt * 16 + l15;
    if (col >= HID) continue;
    for (int mt = 0; mt < 4; mt++) {
      int rbase = row0 + wm + mt * 16 + quad * 4;
      for (int r = 0; r < 4; r++) {
        int row = rbase + r;
        if (row < NN) C[(size_t)row * HID + col] = acc[mt][nt][r];
      }
    }
  }
}

// ---------------------------------------------------------------- W_gcn -> bf16 transposed
__global__ void wconv_kernel(const float* __restrict__ W, __bf16* __restrict__ BT) {
  int i = blockIdx.x * blockDim.x + threadIdx.x;
  if (i >= NP * KP) return;
  int n = i / KP, k = i - n * KP;
  float v = (n < HID && k < HID) ? W[(size_t)k * HID + n] : 0.f;
  BT[i] = (__bf16)v;
}

// ---------------------------------------------------------------- att dots
__global__ __launch_bounds__(128) void att_kernel(
    const float* __restrict__ hbuf, const float* __restrict__ att_src,
    const float* __restrict__ att_dst, float* __restrict__ a_src,
    float* __restrict__ a_dst) {
  __shared__ float row[HID];
  int n = blockIdx.x;
  for (int i = threadIdx.x; i < HID; i += 128) row[i] = hbuf[(size_t)n * HID + i];
  __syncthreads();
  int t = threadIdx.x;
  if (t < 2 * NH) {
    int hh = t % NH;
    const float* att = (t < NH) ? att_src : att_dst;
    float s = 0.f;
    for (int f = 0; f < FF; f++) s += row[hh * FF + f] * att[hh * FF + f];
    if (t < NH) a_src[n * NH + hh] = s;
    else        a_dst[n * NH + hh] = s;
  }
}

// ---------------------------------------------------------------- CSR build
__device__ __forceinline__ void edge_sd(const int* __restrict__ ei, int t,
                                        int& s, int& d) {
  if (t < EE) { s = ei[t]; d = ei[EE + t]; }
  else        { s = t - EE; d = t - EE; }
}

__global__ void count_kernel(const int* __restrict__ ei, int* __restrict__ cnt) {
  int t = blockIdx.x * blockDim.x + threadIdx.x;
  if (t < ET) { int s, d; edge_sd(ei, t, s, d); atomicAdd(&cnt[d], 1); }
}

__global__ __launch_bounds__(1024) void scan_kernel(const int* __restrict__ cnt,
                                                    int* __restrict__ row_ptr) {
  __shared__ int buf[1024];
  __shared__ int carry;
  if (threadIdx.x == 0) carry = 0;
  __syncthreads();
  for (int base = 0; base < NN; base += 1024) {
    int i = base + threadIdx.x;
    int v = (i < NN) ? cnt[i] : 0;
    buf[threadIdx.x] = v;
    __syncthreads();
    for (int off = 1; off < 1024; off <<= 1) {
      int t = (threadIdx.x >= off) ? buf[threadIdx.x - off] : 0;
      __syncthreads();
      buf[threadIdx.x] += t;
      __syncthreads();
    }
    if (i < NN) row_ptr[i] = carry + buf[threadIdx.x] - v;  // exclusive
    __syncthreads();
    if (threadIdx.x == 1023) carry += buf[1023];
    __syncthreads();
  }
  if (threadIdx.x == 0) row_ptr[NN] = carry;
}

__global__ void scatter_kernel(const int* __restrict__ ei,
                               const int* __restrict__ row_ptr,
                               int* __restrict__ fill,
                               int* __restrict__ col_src) {
  int t = blockIdx.x * blockDim.x + threadIdx.x;
  if (t < ET) {
    int s, d; edge_sd(ei, t, s, d);
    int pos = row_ptr[d] + atomicAdd(&fill[d], 1);
    col_src[pos] = s;
  }
}

__global__ void dinv_kernel(const int* __restrict__ row_ptr,
                            float* __restrict__ dinv) {
  int i = blockIdx.x * blockDim.x + threadIdx.x;
  if (i < NN) {
    int d = row_ptr[i + 1] - row_ptr[i];
    dinv[i] = rsqrtf((float)max(d, 1));
  }
}

// ---------------------------------------------------------------- GAT aggregate
#define AGG_BLOCK 832    // 13 waves; threads 0..779 own one feature each
#define CHUNK 32
__global__ __launch_bounds__(AGG_BLOCK) void gat_aggr_kernel(
    const int* __restrict__ row_ptr, const int* __restrict__ col_src,
    const float* __restrict__ a_src, const float* __restrict__ a_dst,
    const float* __restrict__ hbuf, const float* __restrict__ b_gat,
    __bf16* __restrict__ out_bf) {   // [NN][KP] bf16, K zero-padded
  int d = blockIdx.x;
  int beg = row_ptr[d], end = row_ptr[d + 1];
  int tid = threadIdx.x;
  __shared__ float m_s[NH], sum_s[NH];
  __shared__ float alpha_s[CHUNK * NH];
  __shared__ int src_s[CHUNK];
  if (tid < NH) {
    float ad = a_dst[d * NH + tid];
    float m = -1e30f;
    for (int e = beg; e < end; e++) {
      float v = a_src[col_src[e] * NH + tid] + ad;
      v = (v > 0.f) ? v : v * NEG_SLOPE;
      m = fmaxf(m, v);
    }
    float ssum = 0.f;
    for (int e = beg; e < end; e++) {
      float v = a_src[col_src[e] * NH + tid] + ad;
      v = (v > 0.f) ? v : v * NEG_SLOPE;
      ssum += __expf(v - m);
    }
    m_s[tid] = m;
    sum_s[tid] = ssum;
  }
  __syncthreads();
  int f = tid;
  int hh = (f < HID) ? (f / FF) : 0;
  float acc = 0.f;
  for (int c = beg; c < end; c += CHUNK) {
    int ce = min(CHUNK, end - c);
    if (tid < ce * NH) {
      int j = tid / NH, h = tid % NH;
      int s = col_src[c + j];
      float v = a_src[s * NH + h] + a_dst[d * NH + h];
      v = (v > 0.f) ? v : v * NEG_SLOPE;
      alpha_s[j * NH + h] = __expf(v - m_s[h]) / sum_s[h];
      if (h == 0) src_s[j] = s;
    }
    __syncthreads();
    if (f < HID) {
      for (int j = 0; j < ce; j++)
        acc += hbuf[(size_t)src_s[j] * HID + f] * alpha_s[j * NH + hh];
    }
    __syncthreads();
  }
  if (f < HID)
    out_bf[(size_t)d * KP + f] = (__bf16)fmaxf(acc + b_gat[f], 0.f);
  else if (f < KP)
    out_bf[(size_t)d * KP + f] = (__bf16)0.f;
}

// ---------------------------------------------------------------- GCN aggregate
__global__ __launch_bounds__(AGG_BLOCK) void gcn_aggr_kernel(
    const int* __restrict__ row_ptr, const int* __restrict__ col_src,
    const float* __restrict__ dinv, const float* __restrict__ h2,
    const float* __restrict__ b_gcn, float* __restrict__ out2) {
  int d = blockIdx.x;
  int beg = row_ptr[d], end = row_ptr[d + 1];
  int tid = threadIdx.x;
  float dv = dinv[d];
  __shared__ float w_s[CHUNK];
  __shared__ int src_s[CHUNK];
  float acc = 0.f;
  for (int c = beg; c < end; c += CHUNK) {
    int ce = min(CHUNK, end - c);
    if (tid < ce) {
      int s = col_src[c + tid];
      src_s[tid] = s;
      w_s[tid] = dinv[s] * dv;
    }
    __syncthreads();
    if (tid < HID) {
      for (int j = 0; j < ce; j++)
        acc += h2[(size_t)src_s[j] * HID + tid] * w_s[j];
    }
    __syncthreads();
  }
  if (tid < HID)
    out2[(size_t)d * HID + tid] = fmaxf(acc + b_gcn[tid], 0.f);
}

// ---------------------------------------------------------------- pooling
__global__ void bounds_kernel(const int* __restrict__ batch,
                              int* __restrict__ lo, int* __restrict__ hi) {
  int i = blockIdx.x * blockDim.x + threadIdx.x;
  if (i < NN) {
    int g = batch[i];
    atomicMin(&lo[g], i);
    atomicMax(&hi[g], i + 1);
  }
}

__global__ __launch_bounds__(AGG_BLOCK) void pool_kernel(
    const float* __restrict__ out2, const int* __restrict__ lo,
    const int* __restrict__ hi, float* __restrict__ pooled) {
  int g = blockIdx.x;
  int l = lo[g], h = hi[g];
  int f = threadIdx.x;
  if (f >= HID) return;
  float s = 0.f, mx = -1e30f;
  for (int n = l; n < h; n++) {
    float v = out2[(size_t)n * HID + f];
    s += v;
    mx = fmaxf(mx, v);
  }
  if (h <= l) { s = 0.f; mx = 0.f; }
  else s = s / (float)(h - l);
  pooled[(size_t)g * (2 * HID) + f] = s;
  pooled[(size_t)g * (2 * HID) + HID + f] = mx;
}

// ---------------------------------------------------------------- launch
extern "C" void kernel_launch(void* const* d_in, const int* in_sizes, int n_in,
                              void* d_out, int out_size, void* d_ws,
                              size_t ws_size, hipStream_t stream) {
  const float* x        = (const float*)d_in[0];
  const int*   edge_idx = (const int*)d_in[1];
  const int*   batch    = (const int*)d_in[2];
  const float* W_gat    = (const float*)d_in[3];
  const float* att_src  = (const float*)d_in[4];
  const float* att_dst  = (const float*)d_in[5];
  const float* b_gat    = (const float*)d_in[6];
  const float* W_gcn    = (const float*)d_in[7];
  const float* b_gcn    = (const float*)d_in[8];
  const float* W1       = (const float*)d_in[9];
  const float* b1       = (const float*)d_in[10];
  const float* W2       = (const float*)d_in[11];
  const float* b2       = (const float*)d_in[12];
  float* out = (float*)d_out;
  (void)in_sizes; (void)n_in; (void)out_size; (void)ws_size;

  char* ws = (char*)d_ws;
  size_t off = 0;
  auto alloc = [&](size_t bytes) -> void* {
    void* p = ws + off;
    off += (bytes + 255) & ~(size_t)255;
    return p;
  };
  // bufA: h (GEMM1 out), then h2 (MFMA GEMM out)
  float* bufA    = (float*)alloc((size_t)NN * HID * 4);          // 93.6 MB
  // bufR: first 48.2 MB = A_bf (bf16 out_gat, dead after MFMA GEMM);
  //       then out2 fp32 (written by gcn_aggr) — temporally disjoint.
  float* bufR    = (float*)alloc((size_t)NN * HID * 4);          // 93.6 MB
  __bf16* A_bf   = (__bf16*)bufR;                                // [NN][KP]
  __bf16* W_bfT  = (__bf16*)alloc((size_t)NP * KP * 2);          // 1.43 MB
  float* a_src_b = (float*)alloc((size_t)NN * NH * 4);
  float* a_dst_b = (float*)alloc((size_t)NN * NH * 4);
  int*   cnt     = (int*)alloc((size_t)NN * 4);
  int*   fill    = (int*)alloc((size_t)NN * 4);
  int*   row_ptr = (int*)alloc((size_t)(NN + 1) * 4);
  int*   col_src = (int*)alloc((size_t)ET * 4);
  int*   lo      = (int*)alloc((size_t)GG * 4);
  int*   hi      = (int*)alloc((size_t)GG * 4);
  float* dinv    = (float*)alloc((size_t)NN * 4);
  float* pooled  = (float*)alloc((size_t)GG * 2 * HID * 4);
  float* hidfc   = (float*)alloc((size_t)GG * 1500 * 4);

  init_kernel<<<(NN + 255) / 256, 256, 0, stream>>>(cnt, fill, lo, hi);
  wconv_kernel<<<(NP * KP + 255) / 256, 256, 0, stream>>>(W_gcn, W_bfT);

  {  // h = x @ W_gat  (fp32, K=78 — small)
    dim3 grid((HID + BN - 1) / BN, (NN + BM - 1) / BM);
    sgemm_kernel<<<grid, 256, 0, stream>>>(NN, HID, FF, x, W_gat, nullptr, bufA, 0);
  }
  att_kernel<<<NN, 128, 0, stream>>>(bufA, att_src, att_dst, a_src_b, a_dst_b);

  count_kernel<<<(ET + 255) / 256, 256, 0, stream>>>(edge_idx, cnt);
  scan_kernel<<<1, 1024, 0, stream>>>(cnt, row_ptr);
  scatter_kernel<<<(ET + 255) / 256, 256, 0, stream>>>(edge_idx, row_ptr, fill, col_src);
  dinv_kernel<<<(NN + 255) / 256, 256, 0, stream>>>(row_ptr, dinv);

  gat_aggr_kernel<<<NN, AGG_BLOCK, 0, stream>>>(row_ptr, col_src, a_src_b,
                                                a_dst_b, bufA, b_gat, A_bf);
  {  // h2 = out_gat(bf16) @ W_gcn(bf16)  via MFMA -> bufA fp32
    dim3 grid(NP / NT, (NN + MT - 1) / MT);
    gemm_mfma_kernel<<<grid, 256, 0, stream>>>(A_bf, W_bfT, bufA);
  }
  gcn_aggr_kernel<<<NN, AGG_BLOCK, 0, stream>>>(row_ptr, col_src, dinv, bufA,
                                                b_gcn, bufR);

  bounds_kernel<<<(NN + 255) / 256, 256, 0, stream>>>(batch, lo, hi);
  pool_kernel<<<GG, AGG_BLOCK, 0, stream>>>(bufR, lo, hi, pooled);

  {  // hidfc = relu(pooled @ W1 + b1)
    dim3 grid((1500 + BN - 1) / BN, (GG + BM - 1) / BM);
    sgemm_kernel<<<grid, 256, 0, stream>>>(GG, 1500, 2 * HID, pooled, W1, b1, hidfc, 1);
  }
  {  // out = hidfc @ W2 + b2
    dim3 grid((128 + BN - 1) / BN, (GG + BM - 1) / BM);
    sgemm_kernel<<<grid, 256, 0, stream>>>(GG, 128, 1500, hidfc, W2, b2, out, 0);
  }
}

// Round 3
// 1461.662 us; speedup vs baseline: 1.5545x; 1.1401x over previous
//
#include <hip/hip_runtime.h>

#define NN 30000
#define EE 240000
#define ET 270000          // E + N self loops
#define GG 1000
#define NH 10
#define FF 78
#define HID 780
#define NEG_SLOPE 0.2f

// MFMA GEMM geometry (GCN layer: [NN,HID] @ [HID,HID])
#define KP 800             // HID padded to multiple of 32
#define NP 896             // HID padded to multiple of 128
#define MT 128
#define NT 128
#define KB 32

typedef __bf16 bf16_8 __attribute__((ext_vector_type(8)));
typedef float f32x4 __attribute__((ext_vector_type(4)));

__device__ __forceinline__ void async_copy16(const void* g, void* l) {
  __builtin_amdgcn_global_load_lds(
      (const __attribute__((address_space(1))) void*)g,
      (__attribute__((address_space(3))) void*)l, 16, 0, 0);
}

// ---------------------------------------------------------------- init
__global__ void init_kernel(int* __restrict__ cnt, int* __restrict__ fill,
                            int* __restrict__ lo, int* __restrict__ hi) {
  int i = blockIdx.x * blockDim.x + threadIdx.x;
  if (i < NN) { cnt[i] = 0; fill[i] = 0; }
  if (i < GG) { lo[i] = NN; hi[i] = 0; }
}

// ---------------------------------------------------------------- sgemm (fp32)
// C[M,N] = A[M,K] @ B[K,N] (+bias) (relu); optional extra bf16 copy Cbf
#define BM 64
#define BN 64
#define BK 16
__global__ __launch_bounds__(256) void sgemm_kernel(
    int M, int N, int K,
    const float* __restrict__ A, const float* __restrict__ B,
    const float* __restrict__ bias, float* __restrict__ C,
    __bf16* __restrict__ Cbf, int relu) {
  __shared__ float As[BK][BM + 1];
  __shared__ float Bs[BK][BN];
  int tid = threadIdx.x;
  int tx = tid & 15, ty = tid >> 4;
  int row0 = blockIdx.y * BM, col0 = blockIdx.x * BN;
  float acc[4][4] = {};
  for (int k0 = 0; k0 < K; k0 += BK) {
    for (int li = tid; li < BM * BK; li += 256) {
      int m = li >> 4, k = li & 15;
      int gm = row0 + m, gk = k0 + k;
      As[k][m] = (gm < M && gk < K) ? A[(size_t)gm * K + gk] : 0.f;
    }
    for (int li = tid; li < BK * BN; li += 256) {
      int k = li >> 6, n = li & 63;
      int gk = k0 + k, gn = col0 + n;
      Bs[k][n] = (gk < K && gn < N) ? B[(size_t)gk * N + gn] : 0.f;
    }
    __syncthreads();
    for (int k = 0; k < BK; k++) {
      float ra[4], rb[4];
      for (int m = 0; m < 4; m++) ra[m] = As[k][ty * 4 + m];
      for (int n = 0; n < 4; n++) rb[n] = Bs[k][tx * 4 + n];
      for (int m = 0; m < 4; m++)
        for (int n = 0; n < 4; n++)
          acc[m][n] += ra[m] * rb[n];
    }
    __syncthreads();
  }
  for (int m = 0; m < 4; m++) {
    int gm = row0 + ty * 4 + m;
    if (gm >= M) continue;
    for (int n = 0; n < 4; n++) {
      int gn = col0 + tx * 4 + n;
      if (gn >= N) continue;
      float v = acc[m][n];
      if (bias) v += bias[gn];
      if (relu) v = fmaxf(v, 0.f);
      if (C) C[(size_t)gm * N + gn] = v;
      if (Cbf) Cbf[(size_t)gm * N + gn] = (__bf16)v;
    }
  }
}

// ---------------------------------------------------------------- bf16 MFMA GEMM
// h2[NN,HID] (bf16) = A[NN,KP] (bf16, zero-padded K) @ BT[NP,KP]^T (bf16)
__global__ __launch_bounds__(256) void gemm_mfma_kernel(
    const __bf16* __restrict__ A, const __bf16* __restrict__ BT,
    __bf16* __restrict__ C) {
  __shared__ __bf16 As[MT][KB];   // 8 KB
  __shared__ __bf16 Bs[NT][KB];   // 8 KB
  int tid = threadIdx.x;
  int lane = tid & 63;
  int wave = tid >> 6;
  int row0 = blockIdx.y * MT, col0 = blockIdx.x * NT;
  int wm = (wave & 1) * 64;   // wave's 64x64 sub-tile
  int wn = (wave >> 1) * 64;
  int l15 = lane & 15;
  int quad = lane >> 4;
  f32x4 acc[4][4] = {};

  for (int k0 = 0; k0 < KP; k0 += KB) {
    for (int t = 0; t < 2; t++) {
      int c = tid + t * 256;
      int r = c >> 2, kc = c & 3;
      const __bf16* g = A + (size_t)(row0 + r) * KP + k0 + kc * 8;
      char* l = (char*)&As[0][0] + (size_t)((tid & ~63) + t * 256) * 16;
      async_copy16(g, l);
    }
    for (int t = 0; t < 2; t++) {
      int c = tid + t * 256;
      int r = c >> 2, kc = c & 3;
      const __bf16* g = BT + (size_t)(col0 + r) * KP + k0 + kc * 8;
      char* l = (char*)&Bs[0][0] + (size_t)((tid & ~63) + t * 256) * 16;
      async_copy16(g, l);
    }
    __syncthreads();

    bf16_8 af[4], bfv[4];
    for (int mt = 0; mt < 4; mt++)
      af[mt] = *(const bf16_8*)&As[wm + mt * 16 + l15][quad * 8];
    for (int nt = 0; nt < 4; nt++)
      bfv[nt] = *(const bf16_8*)&Bs[wn + nt * 16 + l15][quad * 8];
    for (int mt = 0; mt < 4; mt++)
      for (int nt = 0; nt < 4; nt++)
        acc[mt][nt] = __builtin_amdgcn_mfma_f32_16x16x32_bf16(
            af[mt], bfv[nt], acc[mt][nt], 0, 0, 0);
    __syncthreads();
  }

  // epilogue: C/D layout col=lane&15, row=quad*4+reg — write bf16 directly
  for (int nt = 0; nt < 4; nt++) {
    int col = col0 + wn + nt * 16 + l15;
    if (col >= HID) continue;
    for (int mt = 0; mt < 4; mt++) {
      int rbase = row0 + wm + mt * 16 + quad * 4;
      for (int r = 0; r < 4; r++) {
        int row = rbase + r;
        if (row < NN) C[(size_t)row * HID + col] = (__bf16)acc[mt][nt][r];
      }
    }
  }
}

// ---------------------------------------------------------------- W_gcn -> bf16 transposed
__global__ void wconv_kernel(const float* __restrict__ W, __bf16* __restrict__ BT) {
  int i = blockIdx.x * blockDim.x + threadIdx.x;
  if (i >= NP * KP) return;
  int n = i / KP, k = i - n * KP;
  float v = (n < HID && k < HID) ? W[(size_t)k * HID + n] : 0.f;
  BT[i] = (__bf16)v;
}

// ---------------------------------------------------------------- att dots
__global__ __launch_bounds__(128) void att_kernel(
    const float* __restrict__ hbuf, const float* __restrict__ att_src,
    const float* __restrict__ att_dst, float* __restrict__ a_src,
    float* __restrict__ a_dst) {
  __shared__ float row[HID];
  int n = blockIdx.x;
  for (int i = threadIdx.x; i < HID; i += 128) row[i] = hbuf[(size_t)n * HID + i];
  __syncthreads();
  int t = threadIdx.x;
  if (t < 2 * NH) {
    int hh = t % NH;
    const float* att = (t < NH) ? att_src : att_dst;
    float s = 0.f;
    for (int f = 0; f < FF; f++) s += row[hh * FF + f] * att[hh * FF + f];
    if (t < NH) a_src[n * NH + hh] = s;
    else        a_dst[n * NH + hh] = s;
  }
}

// ---------------------------------------------------------------- CSR build
__device__ __forceinline__ void edge_sd(const int* __restrict__ ei, int t,
                                        int& s, int& d) {
  if (t < EE) { s = ei[t]; d = ei[EE + t]; }
  else        { s = t - EE; d = t - EE; }
}

__global__ void count_kernel(const int* __restrict__ ei, int* __restrict__ cnt) {
  int t = blockIdx.x * blockDim.x + threadIdx.x;
  if (t < ET) { int s, d; edge_sd(ei, t, s, d); atomicAdd(&cnt[d], 1); }
}

__global__ __launch_bounds__(1024) void scan_kernel(const int* __restrict__ cnt,
                                                    int* __restrict__ row_ptr) {
  __shared__ int buf[1024];
  __shared__ int carry;
  if (threadIdx.x == 0) carry = 0;
  __syncthreads();
  for (int base = 0; base < NN; base += 1024) {
    int i = base + threadIdx.x;
    int v = (i < NN) ? cnt[i] : 0;
    buf[threadIdx.x] = v;
    __syncthreads();
    for (int off = 1; off < 1024; off <<= 1) {
      int t = (threadIdx.x >= off) ? buf[threadIdx.x - off] : 0;
      __syncthreads();
      buf[threadIdx.x] += t;
      __syncthreads();
    }
    if (i < NN) row_ptr[i] = carry + buf[threadIdx.x] - v;  // exclusive
    __syncthreads();
    if (threadIdx.x == 1023) carry += buf[1023];
    __syncthreads();
  }
  if (threadIdx.x == 0) row_ptr[NN] = carry;
}

__global__ void scatter_kernel(const int* __restrict__ ei,
                               const int* __restrict__ row_ptr,
                               int* __restrict__ fill,
                               int* __restrict__ col_src) {
  int t = blockIdx.x * blockDim.x + threadIdx.x;
  if (t < ET) {
    int s, d; edge_sd(ei, t, s, d);
    int pos = row_ptr[d] + atomicAdd(&fill[d], 1);
    col_src[pos] = s;
  }
}

__global__ void dinv_kernel(const int* __restrict__ row_ptr,
                            float* __restrict__ dinv) {
  int i = blockIdx.x * blockDim.x + threadIdx.x;
  if (i < NN) {
    int d = row_ptr[i + 1] - row_ptr[i];
    dinv[i] = rsqrtf((float)max(d, 1));
  }
}

// ---------------------------------------------------------------- GAT aggregate
// Single pass: p = exp(leakyrelu(e)) (no max-sub; |e| small), sum per head in
// LDS, divide at epilogue. Gathers bf16 h.
#define AGG_BLOCK 832    // 13 waves; threads 0..779 own one feature each
#define CHUNK 32
__global__ __launch_bounds__(AGG_BLOCK) void gat_aggr_kernel(
    const int* __restrict__ row_ptr, const int* __restrict__ col_src,
    const float* __restrict__ a_src, const float* __restrict__ a_dst,
    const __bf16* __restrict__ h_bf, const float* __restrict__ b_gat,
    __bf16* __restrict__ out_bf) {   // [NN][KP] bf16, K zero-padded
  int d = blockIdx.x;
  int beg = row_ptr[d], end = row_ptr[d + 1];
  int tid = threadIdx.x;
  __shared__ float sum_s[NH], ad_s[NH];
  __shared__ float alpha_s[CHUNK * NH];
  __shared__ int src_s[CHUNK];
  if (tid < NH) {
    sum_s[tid] = 0.f;
    ad_s[tid] = a_dst[d * NH + tid];
  }
  __syncthreads();
  int f = tid;
  int hh = (f < HID) ? (f / FF) : 0;
  float acc = 0.f;
  for (int c = beg; c < end; c += CHUNK) {
    int ce = min(CHUNK, end - c);
    if (tid < ce * NH) {
      int j = tid / NH, h = tid - j * NH;
      int s = col_src[c + j];
      float v = a_src[s * NH + h] + ad_s[h];
      v = (v > 0.f) ? v : v * NEG_SLOPE;
      float p = __expf(v);
      alpha_s[j * NH + h] = p;
      atomicAdd(&sum_s[h], p);
      if (h == 0) src_s[j] = s;
    }
    __syncthreads();
    if (f < HID) {
      for (int j = 0; j < ce; j++)
        acc += (float)h_bf[(size_t)src_s[j] * HID + f] * alpha_s[j * NH + hh];
    }
    __syncthreads();
  }
  if (f < HID)
    out_bf[(size_t)d * KP + f] = (__bf16)fmaxf(acc / sum_s[hh] + b_gat[f], 0.f);
  else if (f < KP)
    out_bf[(size_t)d * KP + f] = (__bf16)0.f;
}

// ---------------------------------------------------------------- GCN aggregate
__global__ __launch_bounds__(AGG_BLOCK) void gcn_aggr_kernel(
    const int* __restrict__ row_ptr, const int* __restrict__ col_src,
    const float* __restrict__ dinv, const __bf16* __restrict__ h2,
    const float* __restrict__ b_gcn, float* __restrict__ out2) {
  int d = blockIdx.x;
  int beg = row_ptr[d], end = row_ptr[d + 1];
  int tid = threadIdx.x;
  float dv = dinv[d];
  __shared__ float w_s[CHUNK];
  __shared__ int src_s[CHUNK];
  float acc = 0.f;
  for (int c = beg; c < end; c += CHUNK) {
    int ce = min(CHUNK, end - c);
    if (tid < ce) {
      int s = col_src[c + tid];
      src_s[tid] = s;
      w_s[tid] = dinv[s] * dv;
    }
    __syncthreads();
    if (tid < HID) {
      for (int j = 0; j < ce; j++)
        acc += (float)h2[(size_t)src_s[j] * HID + tid] * w_s[j];
    }
    __syncthreads();
  }
  if (tid < HID)
    out2[(size_t)d * HID + tid] = fmaxf(acc + b_gcn[tid], 0.f);
}

// ---------------------------------------------------------------- pooling
__global__ void bounds_kernel(const int* __restrict__ batch,
                              int* __restrict__ lo, int* __restrict__ hi) {
  int i = blockIdx.x * blockDim.x + threadIdx.x;
  if (i < NN) {
    int g = batch[i];
    atomicMin(&lo[g], i);
    atomicMax(&hi[g], i + 1);
  }
}

__global__ __launch_bounds__(AGG_BLOCK) void pool_kernel(
    const float* __restrict__ out2, const int* __restrict__ lo,
    const int* __restrict__ hi, float* __restrict__ pooled) {
  int g = blockIdx.x;
  int l = lo[g], h = hi[g];
  int f = threadIdx.x;
  if (f >= HID) return;
  float s = 0.f, mx = -1e30f;
  for (int n = l; n < h; n++) {
    float v = out2[(size_t)n * HID + f];
    s += v;
    mx = fmaxf(mx, v);
  }
  if (h <= l) { s = 0.f; mx = 0.f; }
  else s = s / (float)(h - l);
  pooled[(size_t)g * (2 * HID) + f] = s;
  pooled[(size_t)g * (2 * HID) + HID + f] = mx;
}

// ---------------------------------------------------------------- launch
extern "C" void kernel_launch(void* const* d_in, const int* in_sizes, int n_in,
                              void* d_out, int out_size, void* d_ws,
                              size_t ws_size, hipStream_t stream) {
  const float* x        = (const float*)d_in[0];
  const int*   edge_idx = (const int*)d_in[1];
  const int*   batch    = (const int*)d_in[2];
  const float* W_gat    = (const float*)d_in[3];
  const float* att_src  = (const float*)d_in[4];
  const float* att_dst  = (const float*)d_in[5];
  const float* b_gat    = (const float*)d_in[6];
  const float* W_gcn    = (const float*)d_in[7];
  const float* b_gcn    = (const float*)d_in[8];
  const float* W1       = (const float*)d_in[9];
  const float* b1       = (const float*)d_in[10];
  const float* W2       = (const float*)d_in[11];
  const float* b2       = (const float*)d_in[12];
  float* out = (float*)d_out;
  (void)in_sizes; (void)n_in; (void)out_size; (void)ws_size;

  char* ws = (char*)d_ws;
  size_t off = 0;
  auto alloc = [&](size_t bytes) -> void* {
    void* p = ws + off;
    off += (bytes + 255) & ~(size_t)255;
    return p;
  };
  // bufA: h fp32 (93.6MB); later reused as h2 bf16 (46.8MB)
  float* bufA    = (float*)alloc((size_t)NN * HID * 4);
  // bufR: A_bf bf16 [NN][KP] (48MB, dead after MFMA GEMM); later out2 fp32
  float* bufR    = (float*)alloc((size_t)NN * HID * 4);
  __bf16* A_bf   = (__bf16*)bufR;
  __bf16* h2_bf  = (__bf16*)bufA;                               // [NN][HID]
  __bf16* h_bf   = (__bf16*)alloc((size_t)NN * HID * 2);        // 46.8 MB
  __bf16* W_bfT  = (__bf16*)alloc((size_t)NP * KP * 2);         // 1.43 MB
  float* a_src_b = (float*)alloc((size_t)NN * NH * 4);
  float* a_dst_b = (float*)alloc((size_t)NN * NH * 4);
  int*   cnt     = (int*)alloc((size_t)NN * 4);
  int*   fill    = (int*)alloc((size_t)NN * 4);
  int*   row_ptr = (int*)alloc((size_t)(NN + 1) * 4);
  int*   col_src = (int*)alloc((size_t)ET * 4);
  int*   lo      = (int*)alloc((size_t)GG * 4);
  int*   hi      = (int*)alloc((size_t)GG * 4);
  float* dinv    = (float*)alloc((size_t)NN * 4);
  float* pooled  = (float*)alloc((size_t)GG * 2 * HID * 4);
  float* hidfc   = (float*)alloc((size_t)GG * 1500 * 4);

  init_kernel<<<(NN + 255) / 256, 256, 0, stream>>>(cnt, fill, lo, hi);
  wconv_kernel<<<(NP * KP + 255) / 256, 256, 0, stream>>>(W_gcn, W_bfT);

  {  // h = x @ W_gat  (fp32, + bf16 copy for gathers)
    dim3 grid((HID + BN - 1) / BN, (NN + BM - 1) / BM);
    sgemm_kernel<<<grid, 256, 0, stream>>>(NN, HID, FF, x, W_gat, nullptr,
                                           bufA, h_bf, 0);
  }
  att_kernel<<<NN, 128, 0, stream>>>(bufA, att_src, att_dst, a_src_b, a_dst_b);

  count_kernel<<<(ET + 255) / 256, 256, 0, stream>>>(edge_idx, cnt);
  scan_kernel<<<1, 1024, 0, stream>>>(cnt, row_ptr);
  scatter_kernel<<<(ET + 255) / 256, 256, 0, stream>>>(edge_idx, row_ptr, fill, col_src);
  dinv_kernel<<<(NN + 255) / 256, 256, 0, stream>>>(row_ptr, dinv);

  gat_aggr_kernel<<<NN, AGG_BLOCK, 0, stream>>>(row_ptr, col_src, a_src_b,
                                                a_dst_b, h_bf, b_gat, A_bf);
  {  // h2(bf16) = out_gat(bf16) @ W_gcn(bf16)  via MFMA
    dim3 grid(NP / NT, (NN + MT - 1) / MT);
    gemm_mfma_kernel<<<grid, 256, 0, stream>>>(A_bf, W_bfT, h2_bf);
  }
  gcn_aggr_kernel<<<NN, AGG_BLOCK, 0, stream>>>(row_ptr, col_src, dinv, h2_bf,
                                                b_gcn, bufR);

  bounds_kernel<<<(NN + 255) / 256, 256, 0, stream>>>(batch, lo, hi);
  pool_kernel<<<GG, AGG_BLOCK, 0, stream>>>(bufR, lo, hi, pooled);

  {  // hidfc = relu(pooled @ W1 + b1)
    dim3 grid((1500 + BN - 1) / BN, (GG + BM - 1) / BM);
    sgemm_kernel<<<grid, 256, 0, stream>>>(GG, 1500, 2 * HID, pooled, W1, b1,
                                           hidfc, nullptr, 1);
  }
  {  // out = hidfc @ W2 + b2
    dim3 grid((128 + BN - 1) / BN, (GG + BM - 1) / BM);
    sgemm_kernel<<<grid, 256, 0, stream>>>(GG, 128, 1500, hidfc, W2, b2, out,
                                           nullptr, 0);
  }
}

// Round 4
// 851.620 us; speedup vs baseline: 2.6680x; 1.7163x over previous
//
#include <hip/hip_runtime.h>

#define NN 30000
#define EE 240000
#define ET 270000          // E + N self loops
#define GG 1000
#define NH 10
#define FF 78
#define HID 780
#define NEG_SLOPE 0.2f

// padded dims
#define KP_GCN 800         // HID -> mult of 32
#define NP_HID 896         // HID -> mult of 128
#define KP_X 96            // FF -> mult of 32
#define MP_N 30080         // NN -> mult of 128
#define KP_P 1568          // 2*HID -> mult of 32
#define NP_W1 1536         // 1500 -> mult of 128
#define LD_FC 1504         // 1500 -> mult of 32 (k-pad for GEMM_D)
#define MP_G 1024          // GG -> mult of 128

#define MT 128
#define NT 128
#define KB 32

typedef __bf16 bf16_8 __attribute__((ext_vector_type(8)));
typedef float f32x4 __attribute__((ext_vector_type(4)));

__device__ __forceinline__ void async_copy16(const void* g, void* l) {
  __builtin_amdgcn_global_load_lds(
      (const __attribute__((address_space(1))) void*)g,
      (__attribute__((address_space(3))) void*)l, 16, 0, 0);
}

// ---------------------------------------------------------------- init
__global__ void init_kernel(int* __restrict__ cnt, int* __restrict__ fill,
                            int* __restrict__ lo, int* __restrict__ hi) {
  int i = blockIdx.x * blockDim.x + threadIdx.x;
  if (i < NN) { cnt[i] = 0; fill[i] = 0; }
  if (i < GG) { lo[i] = NN; hi[i] = 0; }
}

// ---------------------------------------------------------------- generic bf16 MFMA GEMM
// C[M, Nout] = A[Mpad, Kp] @ BT[Npad, Kp]^T  (+bias, relu)
// A rows beyond M may be garbage (in-bounds allocation); writes masked.
// Cols in [Nout, ldc) are written as 0 (zero-fills k-pad of downstream GEMM).
template <bool OUT_BF>
__global__ __launch_bounds__(256) void mfma_gemm(
    const __bf16* __restrict__ A, const __bf16* __restrict__ BT,
    float* __restrict__ Cf, __bf16* __restrict__ Cb,
    const float* __restrict__ bias, int M, int Kp, int Nout, int ldc,
    int relu) {
  __shared__ __bf16 As[MT][KB];   // 8 KB
  __shared__ __bf16 Bs[NT][KB];   // 8 KB
  int tid = threadIdx.x;
  int lane = tid & 63, wave = tid >> 6;
  int row0 = blockIdx.y * MT, col0 = blockIdx.x * NT;
  int wm = (wave & 1) * 64, wn = (wave >> 1) * 64;
  int l15 = lane & 15, quad = lane >> 4;
  f32x4 acc[4][4] = {};

  for (int k0 = 0; k0 < Kp; k0 += KB) {
    for (int t = 0; t < 2; t++) {
      int c = tid + t * 256;
      int r = c >> 2, kc = c & 3;
      const __bf16* g = A + (size_t)(row0 + r) * Kp + k0 + kc * 8;
      char* l = (char*)&As[0][0] + (size_t)((tid & ~63) + t * 256) * 16;
      async_copy16(g, l);
    }
    for (int t = 0; t < 2; t++) {
      int c = tid + t * 256;
      int r = c >> 2, kc = c & 3;
      const __bf16* g = BT + (size_t)(col0 + r) * Kp + k0 + kc * 8;
      char* l = (char*)&Bs[0][0] + (size_t)((tid & ~63) + t * 256) * 16;
      async_copy16(g, l);
    }
    __syncthreads();

    bf16_8 af[4], bfv[4];
    for (int mt = 0; mt < 4; mt++)
      af[mt] = *(const bf16_8*)&As[wm + mt * 16 + l15][quad * 8];
    for (int nt = 0; nt < 4; nt++)
      bfv[nt] = *(const bf16_8*)&Bs[wn + nt * 16 + l15][quad * 8];
    for (int mt = 0; mt < 4; mt++)
      for (int nt = 0; nt < 4; nt++)
        acc[mt][nt] = __builtin_amdgcn_mfma_f32_16x16x32_bf16(
            af[mt], bfv[nt], acc[mt][nt], 0, 0, 0);
    __syncthreads();
  }

  // C/D layout: col=lane&15, row=quad*4+reg
  for (int nt = 0; nt < 4; nt++) {
    int col = col0 + wn + nt * 16 + l15;
    if (col >= ldc) continue;
    bool valid = col < Nout;
    float bv = (valid && bias) ? bias[col] : 0.f;
    for (int mt = 0; mt < 4; mt++) {
      int rbase = row0 + wm + mt * 16 + quad * 4;
      for (int r = 0; r < 4; r++) {
        int row = rbase + r;
        if (row >= M) continue;
        float v = 0.f;
        if (valid) {
          v = acc[mt][nt][r] + bv;
          if (relu) v = fmaxf(v, 0.f);
        }
        if (OUT_BF) Cb[(size_t)row * ldc + col] = (__bf16)v;
        else        Cf[(size_t)row * ldc + col] = v;
      }
    }
  }
}

// ---------------------------------------------------------------- conversions
// W[K,N] fp32 -> BT[Np][Kp] bf16 (transposed, zero-padded)
__global__ void wconvT_kernel(const float* __restrict__ W,
                              __bf16* __restrict__ BT, int K, int N, int Kp,
                              int Np) {
  int i = blockIdx.x * blockDim.x + threadIdx.x;
  if (i >= Np * Kp) return;
  int n = i / Kp, k = i - n * Kp;
  BT[i] = (__bf16)((n < N && k < K) ? W[(size_t)k * N + n] : 0.f);
}

__global__ void xconv_kernel(const float* __restrict__ x,
                             __bf16* __restrict__ xb) {
  int i = blockIdx.x * blockDim.x + threadIdx.x;
  if (i >= MP_N * KP_X) return;
  int n = i / KP_X, k = i - n * KP_X;
  xb[i] = (__bf16)((n < NN && k < FF) ? x[(size_t)n * FF + k] : 0.f);
}

// wsd[k][c] (c<10: src head c, c>=10: dst head c-10) = sum_f W_gat[k, h*F+f]*att[h,f]
__global__ void wsd_kernel(const float* __restrict__ W_gat,
                           const float* __restrict__ att_src,
                           const float* __restrict__ att_dst,
                           float* __restrict__ wsd) {
  int i = blockIdx.x * blockDim.x + threadIdx.x;
  if (i >= FF * 2 * NH) return;
  int k = i / (2 * NH), c = i - k * (2 * NH);
  int h = (c < NH) ? c : c - NH;
  const float* att = (c < NH) ? att_src : att_dst;
  float s = 0.f;
  for (int f = 0; f < FF; f++)
    s += W_gat[(size_t)k * HID + h * FF + f] * att[h * FF + f];
  wsd[k * 2 * NH + c] = s;
}

// a_src[n,h], a_dst[n,h] = x[n,:] @ wsd[:,c]  (exact refactor of einsum)
__global__ __launch_bounds__(256) void adot_kernel(
    const float* __restrict__ x, const float* __restrict__ wsd,
    float* __restrict__ a_src, float* __restrict__ a_dst) {
  __shared__ float w_s[FF * 2 * NH];
  for (int i = threadIdx.x; i < FF * 2 * NH; i += 256) w_s[i] = wsd[i];
  __syncthreads();
  int gid = blockIdx.x * 256 + threadIdx.x;
  if (gid >= NN * 2 * NH) return;
  int n = gid / (2 * NH), c = gid - n * (2 * NH);
  float s = 0.f;
  for (int k = 0; k < FF; k++) s += x[(size_t)n * FF + k] * w_s[k * 2 * NH + c];
  if (c < NH) a_src[n * NH + c] = s;
  else        a_dst[n * NH + (c - NH)] = s;
}

// ---------------------------------------------------------------- CSR build
__device__ __forceinline__ void edge_sd(const int* __restrict__ ei, int t,
                                        int& s, int& d) {
  if (t < EE) { s = ei[t]; d = ei[EE + t]; }
  else        { s = t - EE; d = t - EE; }
}

__global__ void count_kernel(const int* __restrict__ ei, int* __restrict__ cnt) {
  int t = blockIdx.x * blockDim.x + threadIdx.x;
  if (t < ET) { int s, d; edge_sd(ei, t, s, d); atomicAdd(&cnt[d], 1); }
}

__global__ __launch_bounds__(1024) void scan_kernel(const int* __restrict__ cnt,
                                                    int* __restrict__ row_ptr) {
  __shared__ int buf[1024];
  __shared__ int carry;
  if (threadIdx.x == 0) carry = 0;
  __syncthreads();
  for (int base = 0; base < NN; base += 1024) {
    int i = base + threadIdx.x;
    int v = (i < NN) ? cnt[i] : 0;
    buf[threadIdx.x] = v;
    __syncthreads();
    for (int off = 1; off < 1024; off <<= 1) {
      int t = (threadIdx.x >= off) ? buf[threadIdx.x - off] : 0;
      __syncthreads();
      buf[threadIdx.x] += t;
      __syncthreads();
    }
    if (i < NN) row_ptr[i] = carry + buf[threadIdx.x] - v;  // exclusive
    __syncthreads();
    if (threadIdx.x == 1023) carry += buf[1023];
    __syncthreads();
  }
  if (threadIdx.x == 0) row_ptr[NN] = carry;
}

__global__ void scatter_kernel(const int* __restrict__ ei,
                               const int* __restrict__ row_ptr,
                               int* __restrict__ fill,
                               int* __restrict__ col_src) {
  int t = blockIdx.x * blockDim.x + threadIdx.x;
  if (t < ET) {
    int s, d; edge_sd(ei, t, s, d);
    int pos = row_ptr[d] + atomicAdd(&fill[d], 1);
    col_src[pos] = s;
  }
}

__global__ void dinv_kernel(const int* __restrict__ row_ptr,
                            float* __restrict__ dinv) {
  int i = blockIdx.x * blockDim.x + threadIdx.x;
  if (i < NN) {
    int d = row_ptr[i + 1] - row_ptr[i];
    dinv[i] = rsqrtf((float)max(d, 1));
  }
}

// ---------------------------------------------------------------- GAT aggregate
#define AGG_BLOCK 832    // 13 waves; threads 0..779 own one feature each
#define CHUNK 32
__global__ __launch_bounds__(AGG_BLOCK) void gat_aggr_kernel(
    const int* __restrict__ row_ptr, const int* __restrict__ col_src,
    const float* __restrict__ a_src, const float* __restrict__ a_dst,
    const __bf16* __restrict__ h_bf, const float* __restrict__ b_gat,
    __bf16* __restrict__ out_bf) {   // [MP_N][KP_GCN] bf16, K zero-padded
  int d = blockIdx.x;
  int beg = row_ptr[d], end = row_ptr[d + 1];
  int tid = threadIdx.x;
  __shared__ float sum_s[NH], ad_s[NH];
  __shared__ float alpha_s[CHUNK * NH];
  __shared__ int src_s[CHUNK];
  if (tid < NH) {
    sum_s[tid] = 0.f;
    ad_s[tid] = a_dst[d * NH + tid];
  }
  __syncthreads();
  int f = tid;
  int hh = (f < HID) ? (f / FF) : 0;
  float acc = 0.f;
  for (int c = beg; c < end; c += CHUNK) {
    int ce = min(CHUNK, end - c);
    if (tid < ce * NH) {
      int j = tid / NH, h = tid - j * NH;
      int s = col_src[c + j];
      float v = a_src[s * NH + h] + ad_s[h];
      v = (v > 0.f) ? v : v * NEG_SLOPE;
      float p = __expf(v);
      alpha_s[j * NH + h] = p;
      atomicAdd(&sum_s[h], p);
      if (h == 0) src_s[j] = s;
    }
    __syncthreads();
    if (f < HID) {
      for (int j = 0; j < ce; j++)
        acc += (float)h_bf[(size_t)src_s[j] * HID + f] * alpha_s[j * NH + hh];
    }
    __syncthreads();
  }
  if (f < HID)
    out_bf[(size_t)d * KP_GCN + f] = (__bf16)fmaxf(acc / sum_s[hh] + b_gat[f], 0.f);
  else if (f < KP_GCN)
    out_bf[(size_t)d * KP_GCN + f] = (__bf16)0.f;
}

// ---------------------------------------------------------------- GCN aggregate
__global__ __launch_bounds__(AGG_BLOCK) void gcn_aggr_kernel(
    const int* __restrict__ row_ptr, const int* __restrict__ col_src,
    const float* __restrict__ dinv, const __bf16* __restrict__ h2,
    const float* __restrict__ b_gcn, float* __restrict__ out2) {
  int d = blockIdx.x;
  int beg = row_ptr[d], end = row_ptr[d + 1];
  int tid = threadIdx.x;
  float dv = dinv[d];
  __shared__ float w_s[CHUNK];
  __shared__ int src_s[CHUNK];
  float acc = 0.f;
  for (int c = beg; c < end; c += CHUNK) {
    int ce = min(CHUNK, end - c);
    if (tid < ce) {
      int s = col_src[c + tid];
      src_s[tid] = s;
      w_s[tid] = dinv[s] * dv;
    }
    __syncthreads();
    if (tid < HID) {
      for (int j = 0; j < ce; j++)
        acc += (float)h2[(size_t)src_s[j] * HID + tid] * w_s[j];
    }
    __syncthreads();
  }
  if (tid < HID)
    out2[(size_t)d * HID + tid] = fmaxf(acc + b_gcn[tid], 0.f);
}

// ---------------------------------------------------------------- pooling
__global__ void bounds_kernel(const int* __restrict__ batch,
                              int* __restrict__ lo, int* __restrict__ hi) {
  int i = blockIdx.x * blockDim.x + threadIdx.x;
  if (i < NN) {
    int g = batch[i];
    atomicMin(&lo[g], i);
    atomicMax(&hi[g], i + 1);
  }
}

// writes bf16 pooled [MP_G][KP_P], k-pad cols zeroed
__global__ __launch_bounds__(AGG_BLOCK) void pool_kernel(
    const float* __restrict__ out2, const int* __restrict__ lo,
    const int* __restrict__ hi, __bf16* __restrict__ pooled) {
  int g = blockIdx.x;
  int l = lo[g], h = hi[g];
  int f = threadIdx.x;
  if (f >= HID) {
    int pad = f - HID;
    if (pad < KP_P - 2 * HID)
      pooled[(size_t)g * KP_P + 2 * HID + pad] = (__bf16)0.f;
    return;
  }
  float s = 0.f, mx = -1e30f;
  for (int n = l; n < h; n++) {
    float v = out2[(size_t)n * HID + f];
    s += v;
    mx = fmaxf(mx, v);
  }
  if (h <= l) { s = 0.f; mx = 0.f; }
  else s = s / (float)(h - l);
  pooled[(size_t)g * KP_P + f] = (__bf16)s;
  pooled[(size_t)g * KP_P + HID + f] = (__bf16)mx;
}

// ---------------------------------------------------------------- launch
extern "C" void kernel_launch(void* const* d_in, const int* in_sizes, int n_in,
                              void* d_out, int out_size, void* d_ws,
                              size_t ws_size, hipStream_t stream) {
  const float* x        = (const float*)d_in[0];
  const int*   edge_idx = (const int*)d_in[1];
  const int*   batch    = (const int*)d_in[2];
  const float* W_gat    = (const float*)d_in[3];
  const float* att_src  = (const float*)d_in[4];
  const float* att_dst  = (const float*)d_in[5];
  const float* b_gat    = (const float*)d_in[6];
  const float* W_gcn    = (const float*)d_in[7];
  const float* b_gcn    = (const float*)d_in[8];
  const float* W1       = (const float*)d_in[9];
  const float* b1       = (const float*)d_in[10];
  const float* W2       = (const float*)d_in[11];
  const float* b2       = (const float*)d_in[12];
  float* out = (float*)d_out;
  (void)in_sizes; (void)n_in; (void)out_size; (void)ws_size;

  char* ws = (char*)d_ws;
  size_t off = 0;
  auto alloc = [&](size_t bytes) -> void* {
    void* p = ws + off;
    off += (bytes + 255) & ~(size_t)255;
    return p;
  };
  // bufR: A_bf bf16 [MP_N][KP_GCN] (48.1MB, dead after GEMM_B); then out2 fp32
  float* bufR     = (float*)alloc((size_t)NN * HID * 4);          // 93.6 MB
  __bf16* A_bf    = (__bf16*)bufR;
  __bf16* h_bf    = (__bf16*)alloc((size_t)NN * HID * 2);         // 46.8 MB
  __bf16* h2_bf   = (__bf16*)alloc((size_t)NN * HID * 2);         // 46.8 MB
  __bf16* x_bf    = (__bf16*)alloc((size_t)MP_N * KP_X * 2);      // 5.8 MB
  __bf16* WgatT   = (__bf16*)alloc((size_t)NP_HID * KP_X * 2);
  __bf16* WgcnT   = (__bf16*)alloc((size_t)NP_HID * KP_GCN * 2);
  __bf16* W1T     = (__bf16*)alloc((size_t)NP_W1 * KP_P * 2);
  __bf16* W2T     = (__bf16*)alloc((size_t)128 * LD_FC * 2);
  __bf16* pooled  = (__bf16*)alloc((size_t)MP_G * KP_P * 2);
  __bf16* hidfc   = (__bf16*)alloc((size_t)MP_G * LD_FC * 2);
  float* wsd      = (float*)alloc((size_t)FF * 2 * NH * 4);
  float* a_src_b  = (float*)alloc((size_t)NN * NH * 4);
  float* a_dst_b  = (float*)alloc((size_t)NN * NH * 4);
  int*   cnt      = (int*)alloc((size_t)NN * 4);
  int*   fill     = (int*)alloc((size_t)NN * 4);
  int*   row_ptr  = (int*)alloc((size_t)(NN + 1) * 4);
  int*   col_src  = (int*)alloc((size_t)ET * 4);
  int*   lo       = (int*)alloc((size_t)GG * 4);
  int*   hi       = (int*)alloc((size_t)GG * 4);
  float* dinv     = (float*)alloc((size_t)NN * 4);

  init_kernel<<<(NN + 255) / 256, 256, 0, stream>>>(cnt, fill, lo, hi);

  // one-time conversions
  xconv_kernel<<<(MP_N * KP_X + 255) / 256, 256, 0, stream>>>(x, x_bf);
  wconvT_kernel<<<(NP_HID * KP_X + 255) / 256, 256, 0, stream>>>(
      W_gat, WgatT, FF, HID, KP_X, NP_HID);
  wconvT_kernel<<<(NP_HID * KP_GCN + 255) / 256, 256, 0, stream>>>(
      W_gcn, WgcnT, HID, HID, KP_GCN, NP_HID);
  wconvT_kernel<<<(NP_W1 * KP_P + 255) / 256, 256, 0, stream>>>(
      W1, W1T, 2 * HID, 1500, KP_P, NP_W1);
  wconvT_kernel<<<(128 * LD_FC + 255) / 256, 256, 0, stream>>>(
      W2, W2T, 1500, 128, LD_FC, 128);
  wsd_kernel<<<(FF * 2 * NH + 255) / 256, 256, 0, stream>>>(
      W_gat, att_src, att_dst, wsd);

  {  // GEMM_A: h_bf = x @ W_gat
    dim3 grid(NP_HID / NT, MP_N / MT);
    mfma_gemm<true><<<grid, 256, 0, stream>>>(x_bf, WgatT, nullptr, h_bf,
                                              nullptr, NN, KP_X, HID, HID, 0);
  }
  adot_kernel<<<(NN * 2 * NH + 255) / 256, 256, 0, stream>>>(x, wsd, a_src_b,
                                                             a_dst_b);

  count_kernel<<<(ET + 255) / 256, 256, 0, stream>>>(edge_idx, cnt);
  scan_kernel<<<1, 1024, 0, stream>>>(cnt, row_ptr);
  scatter_kernel<<<(ET + 255) / 256, 256, 0, stream>>>(edge_idx, row_ptr, fill, col_src);
  dinv_kernel<<<(NN + 255) / 256, 256, 0, stream>>>(row_ptr, dinv);

  gat_aggr_kernel<<<NN, AGG_BLOCK, 0, stream>>>(row_ptr, col_src, a_src_b,
                                                a_dst_b, h_bf, b_gat, A_bf);
  {  // GEMM_B: h2_bf = out_gat @ W_gcn
    dim3 grid(NP_HID / NT, MP_N / MT);
    mfma_gemm<true><<<grid, 256, 0, stream>>>(A_bf, WgcnT, nullptr, h2_bf,
                                              nullptr, NN, KP_GCN, HID, HID, 0);
  }
  gcn_aggr_kernel<<<NN, AGG_BLOCK, 0, stream>>>(row_ptr, col_src, dinv, h2_bf,
                                                b_gcn, bufR);

  bounds_kernel<<<(NN + 255) / 256, 256, 0, stream>>>(batch, lo, hi);
  pool_kernel<<<GG, AGG_BLOCK, 0, stream>>>(bufR, lo, hi, pooled);

  {  // GEMM_C: hidfc = relu(pooled @ W1 + b1), k-pad cols zeroed
    dim3 grid(NP_W1 / NT, MP_G / MT);
    mfma_gemm<true><<<grid, 256, 0, stream>>>(pooled, W1T, nullptr, hidfc, b1,
                                              GG, KP_P, 1500, LD_FC, 1);
  }
  {  // GEMM_D: out = hidfc @ W2 + b2  (fp32 out)
    dim3 grid(1, MP_G / MT);
    mfma_gemm<false><<<grid, 256, 0, stream>>>(hidfc, W2T, out, nullptr, b2,
                                               GG, LD_FC, 128, 128, 0);
  }
}

// Round 5
// 617.205 us; speedup vs baseline: 3.6812x; 1.3798x over previous
//
#include <hip/hip_runtime.h>

#define NN 30000
#define EE 240000
#define ET 270000          // E + N self loops
#define GG 1000
#define NH 10
#define FF 78
#define HID 780
#define NEG_SLOPE 0.2f

// padded dims
#define LD_H 784           // h / h2 / out2 row stride (= 98*8, 16B-vector friendly)
#define KP_GCN 800         // GCN GEMM K (A_bf row stride)
#define NP_HID 896         // col-grid cover for HID-wide GEMMs
#define KP_X 96            // FF -> mult of 32
#define MP_N 30080         // NN -> mult of 128
#define KP_P 1568          // 2*HID -> mult of 32
#define NP_W1 1536         // 1500 -> mult of 128
#define LD_FC 1504         // 1500 -> mult of 32
#define MP_G 1024          // GG -> mult of 128

#define MT 128
#define NT 128
#define KB 32
#define GCH 16             // aggregation edge chunk
#define NBLK 30            // scan blocks (30000/1024)

typedef __bf16 bf16_8 __attribute__((ext_vector_type(8)));
typedef float f32x4 __attribute__((ext_vector_type(4)));

__device__ __forceinline__ void async_copy16(const void* g, void* l) {
  __builtin_amdgcn_global_load_lds(
      (const __attribute__((address_space(1))) void*)g,
      (__attribute__((address_space(3))) void*)l, 16, 0, 0);
}

__device__ __forceinline__ float bf2f(unsigned int bits) {
  return __uint_as_float(bits << 16);
}

// ---------------------------------------------------------------- init
__global__ void init_kernel(int* __restrict__ cnt, int* __restrict__ fill,
                            int* __restrict__ lo, int* __restrict__ hi) {
  int i = blockIdx.x * blockDim.x + threadIdx.x;
  if (i < NN) { cnt[i] = 0; fill[i] = 0; }
  if (i < GG) { lo[i] = NN; hi[i] = 0; }
}

// ---------------------------------------------------------------- generic bf16 MFMA GEMM
// C[M, Nout] = A[Mpad, Kp] @ BT[Npad, Kp]^T  (+bias, relu)
// Cols in [Nout, ldc) written as 0 (zero-fills pads for downstream consumers).
template <bool OUT_BF>
__global__ __launch_bounds__(256) void mfma_gemm(
    const __bf16* __restrict__ A, const __bf16* __restrict__ BT,
    float* __restrict__ Cf, __bf16* __restrict__ Cb,
    const float* __restrict__ bias, int M, int Kp, int Nout, int ldc,
    int relu) {
  __shared__ __bf16 As[MT][KB];
  __shared__ __bf16 Bs[NT][KB];
  int tid = threadIdx.x;
  int lane = tid & 63, wave = tid >> 6;
  int row0 = blockIdx.y * MT, col0 = blockIdx.x * NT;
  int wm = (wave & 1) * 64, wn = (wave >> 1) * 64;
  int l15 = lane & 15, quad = lane >> 4;
  f32x4 acc[4][4] = {};

  for (int k0 = 0; k0 < Kp; k0 += KB) {
    for (int t = 0; t < 2; t++) {
      int c = tid + t * 256;
      int r = c >> 2, kc = c & 3;
      const __bf16* g = A + (size_t)(row0 + r) * Kp + k0 + kc * 8;
      char* l = (char*)&As[0][0] + (size_t)((tid & ~63) + t * 256) * 16;
      async_copy16(g, l);
    }
    for (int t = 0; t < 2; t++) {
      int c = tid + t * 256;
      int r = c >> 2, kc = c & 3;
      const __bf16* g = BT + (size_t)(col0 + r) * Kp + k0 + kc * 8;
      char* l = (char*)&Bs[0][0] + (size_t)((tid & ~63) + t * 256) * 16;
      async_copy16(g, l);
    }
    __syncthreads();

    bf16_8 af[4], bfv[4];
    for (int mt = 0; mt < 4; mt++)
      af[mt] = *(const bf16_8*)&As[wm + mt * 16 + l15][quad * 8];
    for (int nt = 0; nt < 4; nt++)
      bfv[nt] = *(const bf16_8*)&Bs[wn + nt * 16 + l15][quad * 8];
    for (int mt = 0; mt < 4; mt++)
      for (int nt = 0; nt < 4; nt++)
        acc[mt][nt] = __builtin_amdgcn_mfma_f32_16x16x32_bf16(
            af[mt], bfv[nt], acc[mt][nt], 0, 0, 0);
    __syncthreads();
  }

  // C/D layout: col=lane&15, row=quad*4+reg
  for (int nt = 0; nt < 4; nt++) {
    int col = col0 + wn + nt * 16 + l15;
    if (col >= ldc) continue;
    bool valid = col < Nout;
    float bv = (valid && bias) ? bias[col] : 0.f;
    for (int mt = 0; mt < 4; mt++) {
      int rbase = row0 + wm + mt * 16 + quad * 4;
      for (int r = 0; r < 4; r++) {
        int row = rbase + r;
        if (row >= M) continue;
        float v = 0.f;
        if (valid) {
          v = acc[mt][nt][r] + bv;
          if (relu) v = fmaxf(v, 0.f);
        }
        if (OUT_BF) Cb[(size_t)row * ldc + col] = (__bf16)v;
        else        Cf[(size_t)row * ldc + col] = v;
      }
    }
  }
}

// ---------------------------------------------------------------- conversions
__global__ void wconvT_kernel(const float* __restrict__ W,
                              __bf16* __restrict__ BT, int K, int N, int Kp,
                              int Np) {
  int i = blockIdx.x * blockDim.x + threadIdx.x;
  if (i >= Np * Kp) return;
  int n = i / Kp, k = i - n * Kp;
  BT[i] = (__bf16)((n < N && k < K) ? W[(size_t)k * N + n] : 0.f);
}

__global__ void xconv_kernel(const float* __restrict__ x,
                             __bf16* __restrict__ xb) {
  int i = blockIdx.x * blockDim.x + threadIdx.x;
  if (i >= MP_N * KP_X) return;
  int n = i / KP_X, k = i - n * KP_X;
  xb[i] = (__bf16)((n < NN && k < FF) ? x[(size_t)n * FF + k] : 0.f);
}

// wsd[k][c]: c<10 -> src head c, c>=10 -> dst head c-10
__global__ void wsd_kernel(const float* __restrict__ W_gat,
                           const float* __restrict__ att_src,
                           const float* __restrict__ att_dst,
                           float* __restrict__ wsd) {
  int i = blockIdx.x * blockDim.x + threadIdx.x;
  if (i >= FF * 2 * NH) return;
  int k = i / (2 * NH), c = i - k * (2 * NH);
  int h = (c < NH) ? c : c - NH;
  const float* att = (c < NH) ? att_src : att_dst;
  float s = 0.f;
  for (int f = 0; f < FF; f++)
    s += W_gat[(size_t)k * HID + h * FF + f] * att[h * FF + f];
  wsd[k * 2 * NH + c] = s;
}

__global__ __launch_bounds__(256) void adot_kernel(
    const float* __restrict__ x, const float* __restrict__ wsd,
    float* __restrict__ a_src, float* __restrict__ a_dst) {
  __shared__ float w_s[FF * 2 * NH];
  for (int i = threadIdx.x; i < FF * 2 * NH; i += 256) w_s[i] = wsd[i];
  __syncthreads();
  int gid = blockIdx.x * 256 + threadIdx.x;
  if (gid >= NN * 2 * NH) return;
  int n = gid / (2 * NH), c = gid - n * (2 * NH);
  float s = 0.f;
  for (int k = 0; k < FF; k++) s += x[(size_t)n * FF + k] * w_s[k * 2 * NH + c];
  if (c < NH) a_src[n * NH + c] = s;
  else        a_dst[n * NH + (c - NH)] = s;
}

// ---------------------------------------------------------------- CSR build
__device__ __forceinline__ void edge_sd(const int* __restrict__ ei, int t,
                                        int& s, int& d) {
  if (t < EE) { s = ei[t]; d = ei[EE + t]; }
  else        { s = t - EE; d = t - EE; }
}

__global__ void count_kernel(const int* __restrict__ ei, int* __restrict__ cnt) {
  int t = blockIdx.x * blockDim.x + threadIdx.x;
  if (t < ET) { int s, d; edge_sd(ei, t, s, d); atomicAdd(&cnt[d], 1); }
}

// hierarchical scan: per-block exclusive scan + partial totals
__global__ __launch_bounds__(1024) void scan1_kernel(
    const int* __restrict__ cnt, int* __restrict__ row_ptr,
    int* __restrict__ partial) {
  __shared__ int buf[1024];
  int i = blockIdx.x * 1024 + threadIdx.x;
  int v = (i < NN) ? cnt[i] : 0;
  buf[threadIdx.x] = v;
  __syncthreads();
  for (int off = 1; off < 1024; off <<= 1) {
    int t = (threadIdx.x >= off) ? buf[threadIdx.x - off] : 0;
    __syncthreads();
    buf[threadIdx.x] += t;
    __syncthreads();
  }
  if (i < NN) row_ptr[i] = buf[threadIdx.x] - v;
  if (threadIdx.x == 1023) partial[blockIdx.x] = buf[1023];
}

__global__ void scan2_kernel(int* __restrict__ partial,
                             int* __restrict__ offs) {
  if (threadIdx.x == 0) {
    int run = 0;
    for (int b = 0; b < NBLK; b++) { offs[b] = run; run += partial[b]; }
  }
}

__global__ void scan3_kernel(int* __restrict__ row_ptr,
                             const int* __restrict__ offs) {
  int i = blockIdx.x * blockDim.x + threadIdx.x;
  if (i < NN) row_ptr[i] += offs[i >> 10];
  if (i == 0) row_ptr[NN] = ET;
}

// scatter + per-edge unnormalized attention p (CSR order)
__global__ void scatter_kernel(const int* __restrict__ ei,
                               const int* __restrict__ row_ptr,
                               int* __restrict__ fill,
                               const float* __restrict__ a_src,
                               const float* __restrict__ a_dst,
                               int* __restrict__ col_src,
                               float* __restrict__ p_csr) {
  int t = blockIdx.x * blockDim.x + threadIdx.x;
  if (t >= ET) return;
  int s, d; edge_sd(ei, t, s, d);
  int pos = row_ptr[d] + atomicAdd(&fill[d], 1);
  col_src[pos] = s;
#pragma unroll
  for (int h = 0; h < NH; h++) {
    float v = a_src[s * NH + h] + a_dst[d * NH + h];
    v = (v > 0.f) ? v : v * NEG_SLOPE;
    p_csr[(size_t)pos * NH + h] = __expf(v);
  }
}

// inverse softmax denominators per (dst, head)
__global__ void isum_kernel(const int* __restrict__ row_ptr,
                            const float* __restrict__ p_csr,
                            float* __restrict__ inv_sums) {
  int t = blockIdx.x * blockDim.x + threadIdx.x;
  if (t >= NN * NH) return;
  int d = t / NH, h = t - d * NH;
  int beg = row_ptr[d], end = row_ptr[d + 1];
  float s = 0.f;
  for (int e = beg; e < end; e++) s += p_csr[(size_t)e * NH + h];
  inv_sums[t] = 1.f / s;   // s > 0 (self-loop)
}

__global__ void dinv_kernel(const int* __restrict__ row_ptr,
                            float* __restrict__ dinv) {
  int i = blockIdx.x * blockDim.x + threadIdx.x;
  if (i < NN) {
    int d = row_ptr[i + 1] - row_ptr[i];
    dinv[i] = rsqrtf((float)max(d, 1));
  }
}

// ---------------------------------------------------------------- GAT aggregate
// one dst per 128-thread block; thread t owns features [8t, 8t+8)
__global__ __launch_bounds__(128) void gat_aggr_kernel(
    const int* __restrict__ row_ptr, const int* __restrict__ col_src,
    const float* __restrict__ p_csr, const float* __restrict__ inv_sums,
    const __bf16* __restrict__ h_bf, const float* __restrict__ b_gat,
    __bf16* __restrict__ A_bf) {   // [MP_N][KP_GCN], K zero-padded
  int d = blockIdx.x;
  int beg = row_ptr[d], end = row_ptr[d + 1];
  int tid = threadIdx.x;
  __shared__ float inv_s[NH];
  __shared__ float al_s[GCH][NH];
  __shared__ int src_s[GCH];
  if (tid < NH) inv_s[tid] = inv_sums[d * NH + tid];
  __syncthreads();

  int f0 = 8 * tid;
  int h0 = f0 / FF; if (h0 > NH - 1) h0 = NH - 1;
  int split = (h0 + 1) * FF - f0; if (split > 8) split = 8;
  int h1 = (h0 < NH - 1) ? h0 + 1 : NH - 1;
  float acc[8] = {};

  for (int c = beg; c < end; c += GCH) {
    int ce = min(GCH, end - c);
    if (tid < ce) src_s[tid] = col_src[c + tid];
    for (int i = tid; i < ce * NH; i += 128) {
      int j = i / NH, h = i - j * NH;
      al_s[j][h] = p_csr[(size_t)(c + j) * NH + h] * inv_s[h];
    }
    __syncthreads();
    if (tid < 98) {
      for (int j = 0; j < ce; j++) {
        uint4 r = *(const uint4*)(h_bf + (size_t)src_s[j] * LD_H + f0);
        float a0 = al_s[j][h0], a1 = al_s[j][h1];
        unsigned int w[4] = {r.x, r.y, r.z, r.w};
#pragma unroll
        for (int k = 0; k < 8; k++) {
          unsigned int bits = (k & 1) ? (w[k >> 1] >> 16) : (w[k >> 1] & 0xffffu);
          acc[k] += bf2f(bits) * ((k < split) ? a0 : a1);
        }
      }
    }
    __syncthreads();
  }
  if (tid < 100) {   // covers stride 800 incl. zero pad
    bf16_8 ov;
#pragma unroll
    for (int k = 0; k < 8; k++) {
      int f = f0 + k;
      float val = 0.f;
      if (tid < 98 && f < HID) val = fmaxf(acc[k] + b_gat[f], 0.f);
      ov[k] = (__bf16)val;
    }
    *(bf16_8*)(A_bf + (size_t)d * KP_GCN + f0) = ov;
  }
}

// ---------------------------------------------------------------- GCN aggregate
__global__ __launch_bounds__(128) void gcn_aggr_kernel(
    const int* __restrict__ row_ptr, const int* __restrict__ col_src,
    const float* __restrict__ dinv, const __bf16* __restrict__ h2,
    const float* __restrict__ b_gcn, __bf16* __restrict__ out2) {
  int d = blockIdx.x;
  int beg = row_ptr[d], end = row_ptr[d + 1];
  int tid = threadIdx.x;
  float dv = dinv[d];
  __shared__ float w_s[GCH];
  __shared__ int src_s[GCH];
  int f0 = 8 * tid;
  float acc[8] = {};
  for (int c = beg; c < end; c += GCH) {
    int ce = min(GCH, end - c);
    if (tid < ce) {
      int s = col_src[c + tid];
      src_s[tid] = s;
      w_s[tid] = dinv[s] * dv;
    }
    __syncthreads();
    if (tid < 98) {
      for (int j = 0; j < ce; j++) {
        uint4 r = *(const uint4*)(h2 + (size_t)src_s[j] * LD_H + f0);
        float w = w_s[j];
        unsigned int wb[4] = {r.x, r.y, r.z, r.w};
#pragma unroll
        for (int k = 0; k < 8; k++) {
          unsigned int bits = (k & 1) ? (wb[k >> 1] >> 16) : (wb[k >> 1] & 0xffffu);
          acc[k] += bf2f(bits) * w;
        }
      }
    }
    __syncthreads();
  }
  if (tid < 98) {
    bf16_8 ov;
#pragma unroll
    for (int k = 0; k < 8; k++) {
      int f = f0 + k;
      float val = (f < HID) ? fmaxf(acc[k] + b_gcn[f], 0.f) : 0.f;
      ov[k] = (__bf16)val;
    }
    *(bf16_8*)(out2 + (size_t)d * LD_H + f0) = ov;
  }
}

// ---------------------------------------------------------------- pooling
__global__ void bounds_kernel(const int* __restrict__ batch,
                              int* __restrict__ lo, int* __restrict__ hi) {
  int i = blockIdx.x * blockDim.x + threadIdx.x;
  if (i < NN) {
    int g = batch[i];
    atomicMin(&lo[g], i);
    atomicMax(&hi[g], i + 1);
  }
}

// writes bf16 pooled [MP_G][KP_P], k-pad cols zeroed
__global__ __launch_bounds__(832) void pool_kernel(
    const __bf16* __restrict__ out2, const int* __restrict__ lo,
    const int* __restrict__ hi, __bf16* __restrict__ pooled) {
  int g = blockIdx.x;
  int l = lo[g], h = hi[g];
  int f = threadIdx.x;
  if (f >= HID) {
    int pad = f - HID;
    if (pad < KP_P - 2 * HID)
      pooled[(size_t)g * KP_P + 2 * HID + pad] = (__bf16)0.f;
    return;
  }
  float s = 0.f, mx = -1e30f;
  for (int n = l; n < h; n++) {
    float v = (float)out2[(size_t)n * LD_H + f];
    s += v;
    mx = fmaxf(mx, v);
  }
  if (h <= l) { s = 0.f; mx = 0.f; }
  else s = s / (float)(h - l);
  pooled[(size_t)g * KP_P + f] = (__bf16)s;
  pooled[(size_t)g * KP_P + HID + f] = (__bf16)mx;
}

// ---------------------------------------------------------------- launch
extern "C" void kernel_launch(void* const* d_in, const int* in_sizes, int n_in,
                              void* d_out, int out_size, void* d_ws,
                              size_t ws_size, hipStream_t stream) {
  const float* x        = (const float*)d_in[0];
  const int*   edge_idx = (const int*)d_in[1];
  const int*   batch    = (const int*)d_in[2];
  const float* W_gat    = (const float*)d_in[3];
  const float* att_src  = (const float*)d_in[4];
  const float* att_dst  = (const float*)d_in[5];
  const float* b_gat    = (const float*)d_in[6];
  const float* W_gcn    = (const float*)d_in[7];
  const float* b_gcn    = (const float*)d_in[8];
  const float* W1       = (const float*)d_in[9];
  const float* b1       = (const float*)d_in[10];
  const float* W2       = (const float*)d_in[11];
  const float* b2       = (const float*)d_in[12];
  float* out = (float*)d_out;
  (void)in_sizes; (void)n_in; (void)out_size; (void)ws_size;

  char* ws = (char*)d_ws;
  size_t off = 0;
  auto alloc = [&](size_t bytes) -> void* {
    void* p = ws + off;
    off += (bytes + 255) & ~(size_t)255;
    return p;
  };
  // bufR: first 48.1MB = A_bf [MP_N][KP_GCN] (dead after GEMM_B); then out2
  // bf16 [NN][LD_H] (47MB) written by gcn_aggr. Region sized for out2.
  char*  bufR     = (char*)alloc((size_t)MP_N * KP_GCN * 2);      // 48.1 MB
  __bf16* A_bf    = (__bf16*)bufR;
  __bf16* out2b   = (__bf16*)bufR;                                // overlays A_bf
  __bf16* h_bf    = (__bf16*)alloc((size_t)MP_N * LD_H * 2);      // 47.2 MB
  __bf16* h2_bf   = (__bf16*)alloc((size_t)MP_N * LD_H * 2);      // 47.2 MB
  __bf16* x_bf    = (__bf16*)alloc((size_t)MP_N * KP_X * 2);      // 5.8 MB
  __bf16* WgatT   = (__bf16*)alloc((size_t)NP_HID * KP_X * 2);
  __bf16* WgcnT   = (__bf16*)alloc((size_t)NP_HID * KP_GCN * 2);
  __bf16* W1T     = (__bf16*)alloc((size_t)NP_W1 * KP_P * 2);
  __bf16* W2T     = (__bf16*)alloc((size_t)128 * LD_FC * 2);
  __bf16* pooled  = (__bf16*)alloc((size_t)MP_G * KP_P * 2);
  __bf16* hidfc   = (__bf16*)alloc((size_t)MP_G * LD_FC * 2);
  float* wsd      = (float*)alloc((size_t)FF * 2 * NH * 4);
  float* a_src_b  = (float*)alloc((size_t)NN * NH * 4);
  float* a_dst_b  = (float*)alloc((size_t)NN * NH * 4);
  float* p_csr    = (float*)alloc((size_t)ET * NH * 4);           // 10.8 MB
  float* inv_sums = (float*)alloc((size_t)NN * NH * 4);           // 1.2 MB
  int*   cnt      = (int*)alloc((size_t)NN * 4);
  int*   fill     = (int*)alloc((size_t)NN * 4);
  int*   row_ptr  = (int*)alloc((size_t)(NN + 1) * 4);
  int*   col_src  = (int*)alloc((size_t)ET * 4);
  int*   partial  = (int*)alloc((size_t)NBLK * 4);
  int*   offs     = (int*)alloc((size_t)NBLK * 4);
  int*   lo       = (int*)alloc((size_t)GG * 4);
  int*   hi       = (int*)alloc((size_t)GG * 4);
  float* dinv     = (float*)alloc((size_t)NN * 4);

  init_kernel<<<(NN + 255) / 256, 256, 0, stream>>>(cnt, fill, lo, hi);

  // one-time conversions
  xconv_kernel<<<(MP_N * KP_X + 255) / 256, 256, 0, stream>>>(x, x_bf);
  wconvT_kernel<<<(NP_HID * KP_X + 255) / 256, 256, 0, stream>>>(
      W_gat, WgatT, FF, HID, KP_X, NP_HID);
  wconvT_kernel<<<(NP_HID * KP_GCN + 255) / 256, 256, 0, stream>>>(
      W_gcn, WgcnT, HID, HID, KP_GCN, NP_HID);
  wconvT_kernel<<<(NP_W1 * KP_P + 255) / 256, 256, 0, stream>>>(
      W1, W1T, 2 * HID, 1500, KP_P, NP_W1);
  wconvT_kernel<<<(128 * LD_FC + 255) / 256, 256, 0, stream>>>(
      W2, W2T, 1500, 128, LD_FC, 128);
  wsd_kernel<<<(FF * 2 * NH + 255) / 256, 256, 0, stream>>>(
      W_gat, att_src, att_dst, wsd);

  {  // GEMM_A: h_bf = x @ W_gat  (ldc 784, zero-pad 780..783)
    dim3 grid(NP_HID / NT, MP_N / MT);
    mfma_gemm<true><<<grid, 256, 0, stream>>>(x_bf, WgatT, nullptr, h_bf,
                                              nullptr, NN, KP_X, HID, LD_H, 0);
  }
  adot_kernel<<<(NN * 2 * NH + 255) / 256, 256, 0, stream>>>(x, wsd, a_src_b,
                                                             a_dst_b);

  count_kernel<<<(ET + 255) / 256, 256, 0, stream>>>(edge_idx, cnt);
  scan1_kernel<<<NBLK, 1024, 0, stream>>>(cnt, row_ptr, partial);
  scan2_kernel<<<1, 64, 0, stream>>>(partial, offs);
  scan3_kernel<<<(NN + 255) / 256, 256, 0, stream>>>(row_ptr, offs);
  scatter_kernel<<<(ET + 255) / 256, 256, 0, stream>>>(
      edge_idx, row_ptr, fill, a_src_b, a_dst_b, col_src, p_csr);
  isum_kernel<<<(NN * NH + 255) / 256, 256, 0, stream>>>(row_ptr, p_csr,
                                                         inv_sums);
  dinv_kernel<<<(NN + 255) / 256, 256, 0, stream>>>(row_ptr, dinv);

  gat_aggr_kernel<<<NN, 128, 0, stream>>>(row_ptr, col_src, p_csr, inv_sums,
                                          h_bf, b_gat, A_bf);
  {  // GEMM_B: h2_bf = out_gat @ W_gcn  (ldc 784, zero-pad)
    dim3 grid(NP_HID / NT, MP_N / MT);
    mfma_gemm<true><<<grid, 256, 0, stream>>>(A_bf, WgcnT, nullptr, h2_bf,
                                              nullptr, NN, KP_GCN, HID, LD_H, 0);
  }
  gcn_aggr_kernel<<<NN, 128, 0, stream>>>(row_ptr, col_src, dinv, h2_bf,
                                          b_gcn, out2b);

  bounds_kernel<<<(NN + 255) / 256, 256, 0, stream>>>(batch, lo, hi);
  pool_kernel<<<GG, 832, 0, stream>>>(out2b, lo, hi, pooled);

  {  // GEMM_C: hidfc = relu(pooled @ W1 + b1)
    dim3 grid(NP_W1 / NT, MP_G / MT);
    mfma_gemm<true><<<grid, 256, 0, stream>>>(pooled, W1T, nullptr, hidfc, b1,
                                              GG, KP_P, 1500, LD_FC, 1);
  }
  {  // GEMM_D: out = hidfc @ W2 + b2  (fp32 out)
    dim3 grid(1, MP_G / MT);
    mfma_gemm<false><<<grid, 256, 0, stream>>>(hidfc, W2T, out, nullptr, b2,
                                               GG, LD_FC, 128, 128, 0);
  }
}

// Round 6
// 612.126 us; speedup vs baseline: 3.7118x; 1.0083x over previous
//
#include <hip/hip_runtime.h>

#define NN 30000
#define EE 240000
#define ET 270000          // E + N self loops
#define GG 1000
#define NH 10
#define FF 78
#define HID 780
#define NEG_SLOPE 0.2f

// padded dims
#define LD_H 784           // h / h2 / out2 row stride (= 98*8)
#define KP_GCN 800         // GCN GEMM K (A_bf row stride)
#define NP_HID 896         // col-grid cover for HID-wide GEMMs
#define KP_X 96            // FF -> mult of 32
#define MP_N 30080         // NN -> mult of 128
#define KP_P 1568          // 2*HID -> mult of 32
#define NP_W1 1536         // 1500 -> mult of 128
#define LD_FC 1504         // 1500 -> mult of 32
#define MP_G 1024          // GG -> mult of 128

#define MT 128
#define NT 128
#define KB 32
#define GCH 16             // aggregation edge chunk
#define NBLK 30            // scan blocks (30000/1024)

typedef __bf16 bf16_8 __attribute__((ext_vector_type(8)));
typedef float f32x4 __attribute__((ext_vector_type(4)));

__device__ __forceinline__ void async_copy16(const void* g, void* l) {
  __builtin_amdgcn_global_load_lds(
      (const __attribute__((address_space(1))) void*)g,
      (__attribute__((address_space(3))) void*)l, 16, 0, 0);
}

__device__ __forceinline__ float bf2f(unsigned int bits) {
  return __uint_as_float(bits << 16);
}

// ---------------------------------------------------------------- init
__global__ void init_kernel(int* __restrict__ cnt, int* __restrict__ fill,
                            int* __restrict__ lo, int* __restrict__ hi) {
  int i = blockIdx.x * blockDim.x + threadIdx.x;
  if (i < NN) { cnt[i] = 0; fill[i] = 0; }
  if (i < GG) { lo[i] = NN; hi[i] = 0; }
}

// ---------------------------------------------------------------- generic bf16 MFMA GEMM
// C[M, Nout] = A[Mpad, Kp] @ BT[Npad, Kp]^T  (+bias, relu)
// Cols in [Nout, ldc) written as 0. LDS is chunk-major [kc][r][8] so the
// 16 fragment-read lanes stride 16B -> 2-way bank aliasing (free).
// rp > 0: XCD-partitioned 1D swizzle — partition p=bid&7 owns rp row-tiles,
// col-tiles innermost, so each A row-tile is fetched by exactly one XCD.
template <bool OUT_BF>
__global__ __launch_bounds__(256) void mfma_gemm(
    const __bf16* __restrict__ A, const __bf16* __restrict__ BT,
    float* __restrict__ Cf, __bf16* __restrict__ Cb,
    const float* __restrict__ bias, int M, int Kp, int Nout, int ldc,
    int relu, int rp, int nct, int mtiles) {
  __shared__ __bf16 As[4][MT][8];
  __shared__ __bf16 Bs[4][NT][8];
  int rt, ct;
  if (rp > 0) {
    int bid = blockIdx.x;
    int p = bid & 7, s = bid >> 3;
    int q = s / nct;
    rt = p * rp + q;
    ct = s - q * nct;
    if (rt >= mtiles) return;
  } else {
    rt = blockIdx.y; ct = blockIdx.x;
  }
  int row0 = rt * MT, col0 = ct * NT;
  int tid = threadIdx.x;
  int lane = tid & 63, wave = tid >> 6;
  int wm = (wave & 1) * 64, wn = (wave >> 1) * 64;
  int l15 = lane & 15, quad = lane >> 4;
  f32x4 acc[4][4] = {};

  for (int k0 = 0; k0 < Kp; k0 += KB) {
    for (int t = 0; t < 2; t++) {
      int base = t * 256 + wave * 64;      // uniform per wave
      int s = base + lane;
      int kc = s >> 7, r = s & 127;
      const __bf16* g = A + (size_t)(row0 + r) * Kp + k0 + kc * 8;
      char* l = (char*)&As[0][0][0] + (size_t)base * 16;
      async_copy16(g, l);
    }
    for (int t = 0; t < 2; t++) {
      int base = t * 256 + wave * 64;
      int s = base + lane;
      int kc = s >> 7, r = s & 127;
      const __bf16* g = BT + (size_t)(col0 + r) * Kp + k0 + kc * 8;
      char* l = (char*)&Bs[0][0][0] + (size_t)base * 16;
      async_copy16(g, l);
    }
    __syncthreads();

    bf16_8 af[4], bfv[4];
    for (int mt = 0; mt < 4; mt++)
      af[mt] = *(const bf16_8*)&As[quad][wm + mt * 16 + l15][0];
    for (int nt = 0; nt < 4; nt++)
      bfv[nt] = *(const bf16_8*)&Bs[quad][wn + nt * 16 + l15][0];
    for (int mt = 0; mt < 4; mt++)
      for (int nt = 0; nt < 4; nt++)
        acc[mt][nt] = __builtin_amdgcn_mfma_f32_16x16x32_bf16(
            af[mt], bfv[nt], acc[mt][nt], 0, 0, 0);
    __syncthreads();
  }

  // C/D layout: col=lane&15, row=quad*4+reg
  for (int nt = 0; nt < 4; nt++) {
    int col = col0 + wn + nt * 16 + l15;
    if (col >= ldc) continue;
    bool valid = col < Nout;
    float bv = (valid && bias) ? bias[col] : 0.f;
    for (int mt = 0; mt < 4; mt++) {
      int rbase = row0 + wm + mt * 16 + quad * 4;
      for (int r = 0; r < 4; r++) {
        int row = rbase + r;
        if (row >= M) continue;
        float v = 0.f;
        if (valid) {
          v = acc[mt][nt][r] + bv;
          if (relu) v = fmaxf(v, 0.f);
        }
        if (OUT_BF) Cb[(size_t)row * ldc + col] = (__bf16)v;
        else        Cf[(size_t)row * ldc + col] = v;
      }
    }
  }
}

// ---------------------------------------------------------------- conversions
__global__ void wconvT_kernel(const float* __restrict__ W,
                              __bf16* __restrict__ BT, int K, int N, int Kp,
                              int Np) {
  int i = blockIdx.x * blockDim.x + threadIdx.x;
  if (i >= Np * Kp) return;
  int n = i / Kp, k = i - n * Kp;
  BT[i] = (__bf16)((n < N && k < K) ? W[(size_t)k * N + n] : 0.f);
}

__global__ void xconv_kernel(const float* __restrict__ x,
                             __bf16* __restrict__ xb) {
  int i = blockIdx.x * blockDim.x + threadIdx.x;
  if (i >= MP_N * KP_X) return;
  int n = i / KP_X, k = i - n * KP_X;
  xb[i] = (__bf16)((n < NN && k < FF) ? x[(size_t)n * FF + k] : 0.f);
}

// wsd[k][c]: c<10 -> src head c, c>=10 -> dst head c-10
__global__ void wsd_kernel(const float* __restrict__ W_gat,
                           const float* __restrict__ att_src,
                           const float* __restrict__ att_dst,
                           float* __restrict__ wsd) {
  int i = blockIdx.x * blockDim.x + threadIdx.x;
  if (i >= FF * 2 * NH) return;
  int k = i / (2 * NH), c = i - k * (2 * NH);
  int h = (c < NH) ? c : c - NH;
  const float* att = (c < NH) ? att_src : att_dst;
  float s = 0.f;
  for (int f = 0; f < FF; f++)
    s += W_gat[(size_t)k * HID + h * FF + f] * att[h * FF + f];
  wsd[k * 2 * NH + c] = s;
}

__global__ __launch_bounds__(256) void adot_kernel(
    const float* __restrict__ x, const float* __restrict__ wsd,
    float* __restrict__ a_src, float* __restrict__ a_dst) {
  __shared__ float w_s[FF * 2 * NH];
  for (int i = threadIdx.x; i < FF * 2 * NH; i += 256) w_s[i] = wsd[i];
  __syncthreads();
  int gid = blockIdx.x * 256 + threadIdx.x;
  if (gid >= NN * 2 * NH) return;
  int n = gid / (2 * NH), c = gid - n * (2 * NH);
  float s = 0.f;
  for (int k = 0; k < FF; k++) s += x[(size_t)n * FF + k] * w_s[k * 2 * NH + c];
  if (c < NH) a_src[n * NH + c] = s;
  else        a_dst[n * NH + (c - NH)] = s;
}

// ---------------------------------------------------------------- CSR build
__device__ __forceinline__ void edge_sd(const int* __restrict__ ei, int t,
                                        int& s, int& d) {
  if (t < EE) { s = ei[t]; d = ei[EE + t]; }
  else        { s = t - EE; d = t - EE; }
}

// count degrees + graph bounds (fused)
__global__ void count_kernel(const int* __restrict__ ei,
                             const int* __restrict__ batch,
                             int* __restrict__ cnt, int* __restrict__ lo,
                             int* __restrict__ hi) {
  int t = blockIdx.x * blockDim.x + threadIdx.x;
  if (t < ET) { int s, d; edge_sd(ei, t, s, d); atomicAdd(&cnt[d], 1); }
  if (t < NN) {
    int g = batch[t];
    atomicMin(&lo[g], t);
    atomicMax(&hi[g], t + 1);
  }
}

__global__ __launch_bounds__(1024) void scan1_kernel(
    const int* __restrict__ cnt, int* __restrict__ row_ptr,
    int* __restrict__ partial) {
  __shared__ int buf[1024];
  int i = blockIdx.x * 1024 + threadIdx.x;
  int v = (i < NN) ? cnt[i] : 0;
  buf[threadIdx.x] = v;
  __syncthreads();
  for (int off = 1; off < 1024; off <<= 1) {
    int t = (threadIdx.x >= off) ? buf[threadIdx.x - off] : 0;
    __syncthreads();
    buf[threadIdx.x] += t;
    __syncthreads();
  }
  if (i < NN) row_ptr[i] = buf[threadIdx.x] - v;
  if (threadIdx.x == 1023) partial[blockIdx.x] = buf[1023];
}

__global__ void scan2_kernel(int* __restrict__ partial,
                             int* __restrict__ offs) {
  if (threadIdx.x == 0) {
    int run = 0;
    for (int b = 0; b < NBLK; b++) { offs[b] = run; run += partial[b]; }
  }
}

// add block offsets + dinv from degree (fused)
__global__ void scan3_kernel(int* __restrict__ row_ptr,
                             const int* __restrict__ offs,
                             const int* __restrict__ cnt,
                             float* __restrict__ dinv) {
  int i = blockIdx.x * blockDim.x + threadIdx.x;
  if (i < NN) {
    row_ptr[i] += offs[i >> 10];
    dinv[i] = rsqrtf((float)max(cnt[i], 1));
  }
  if (i == 0) row_ptr[NN] = ET;
}

// scatter + per-edge unnormalized attention p (CSR order)
__global__ void scatter_kernel(const int* __restrict__ ei,
                               const int* __restrict__ row_ptr,
                               int* __restrict__ fill,
                               const float* __restrict__ a_src,
                               const float* __restrict__ a_dst,
                               int* __restrict__ col_src,
                               float* __restrict__ p_csr) {
  int t = blockIdx.x * blockDim.x + threadIdx.x;
  if (t >= ET) return;
  int s, d; edge_sd(ei, t, s, d);
  int pos = row_ptr[d] + atomicAdd(&fill[d], 1);
  col_src[pos] = s;
#pragma unroll
  for (int h = 0; h < NH; h++) {
    float v = a_src[s * NH + h] + a_dst[d * NH + h];
    v = (v > 0.f) ? v : v * NEG_SLOPE;
    p_csr[(size_t)pos * NH + h] = __expf(v);
  }
}

// ---------------------------------------------------------------- GAT aggregate
// one dst per 128-thread block; thread t owns features [8t, 8t+8).
// Unnormalized accumulate; per-head sums in LDS; divide at epilogue.
__global__ __launch_bounds__(128) void gat_aggr_kernel(
    const int* __restrict__ row_ptr, const int* __restrict__ col_src,
    const float* __restrict__ p_csr, const __bf16* __restrict__ h_bf,
    const float* __restrict__ b_gat, __bf16* __restrict__ A_bf) {
  int d = blockIdx.x;
  int beg = row_ptr[d], end = row_ptr[d + 1];
  int tid = threadIdx.x;
  __shared__ float sum_s[NH];
  __shared__ float al_s[GCH][NH];
  __shared__ int src_s[GCH];
  if (tid < NH) sum_s[tid] = 0.f;
  __syncthreads();

  int f0 = 8 * tid;
  int h0 = f0 / FF; if (h0 > NH - 1) h0 = NH - 1;
  int split = (h0 + 1) * FF - f0; if (split > 8) split = 8;
  int h1 = (h0 < NH - 1) ? h0 + 1 : NH - 1;
  float acc[8] = {};

  for (int c = beg; c < end; c += GCH) {
    int ce = min(GCH, end - c);
    if (tid < ce) src_s[tid] = col_src[c + tid];
    for (int i = tid; i < ce * NH; i += 128) {
      int j = i / NH, h = i - j * NH;
      float p = p_csr[(size_t)(c + j) * NH + h];
      al_s[j][h] = p;
      atomicAdd(&sum_s[h], p);
    }
    __syncthreads();
    if (tid < 98) {
      for (int j = 0; j < ce; j++) {
        uint4 r = *(const uint4*)(h_bf + (size_t)src_s[j] * LD_H + f0);
        float a0 = al_s[j][h0], a1 = al_s[j][h1];
        unsigned int w[4] = {r.x, r.y, r.z, r.w};
#pragma unroll
        for (int k = 0; k < 8; k++) {
          unsigned int bits = (k & 1) ? (w[k >> 1] >> 16) : (w[k >> 1] & 0xffffu);
          acc[k] += bf2f(bits) * ((k < split) ? a0 : a1);
        }
      }
    }
    __syncthreads();
  }
  if (tid < 100) {   // covers stride 800 incl. zero pad
    float inv0 = 0.f, inv1 = 0.f;
    if (tid < 98) { inv0 = 1.f / sum_s[h0]; inv1 = 1.f / sum_s[h1]; }
    bf16_8 ov;
#pragma unroll
    for (int k = 0; k < 8; k++) {
      int f = f0 + k;
      float val = 0.f;
      if (tid < 98 && f < HID)
        val = fmaxf(acc[k] * ((k < split) ? inv0 : inv1) + b_gat[f], 0.f);
      ov[k] = (__bf16)val;
    }
    *(bf16_8*)(A_bf + (size_t)d * KP_GCN + f0) = ov;
  }
}

// ---------------------------------------------------------------- GCN aggregate
__global__ __launch_bounds__(128) void gcn_aggr_kernel(
    const int* __restrict__ row_ptr, const int* __restrict__ col_src,
    const float* __restrict__ dinv, const __bf16* __restrict__ h2,
    const float* __restrict__ b_gcn, __bf16* __restrict__ out2) {
  int d = blockIdx.x;
  int beg = row_ptr[d], end = row_ptr[d + 1];
  int tid = threadIdx.x;
  float dv = dinv[d];
  __shared__ float w_s[GCH];
  __shared__ int src_s[GCH];
  int f0 = 8 * tid;
  float acc[8] = {};
  for (int c = beg; c < end; c += GCH) {
    int ce = min(GCH, end - c);
    if (tid < ce) {
      int s = col_src[c + tid];
      src_s[tid] = s;
      w_s[tid] = dinv[s] * dv;
    }
    __syncthreads();
    if (tid < 98) {
      for (int j = 0; j < ce; j++) {
        uint4 r = *(const uint4*)(h2 + (size_t)src_s[j] * LD_H + f0);
        float w = w_s[j];
        unsigned int wb[4] = {r.x, r.y, r.z, r.w};
#pragma unroll
        for (int k = 0; k < 8; k++) {
          unsigned int bits = (k & 1) ? (wb[k >> 1] >> 16) : (wb[k >> 1] & 0xffffu);
          acc[k] += bf2f(bits) * w;
        }
      }
    }
    __syncthreads();
  }
  if (tid < 98) {
    bf16_8 ov;
#pragma unroll
    for (int k = 0; k < 8; k++) {
      int f = f0 + k;
      float val = (f < HID) ? fmaxf(acc[k] + b_gcn[f], 0.f) : 0.f;
      ov[k] = (__bf16)val;
    }
    *(bf16_8*)(out2 + (size_t)d * LD_H + f0) = ov;
  }
}

// ---------------------------------------------------------------- pooling
__global__ __launch_bounds__(832) void pool_kernel(
    const __bf16* __restrict__ out2, const int* __restrict__ lo,
    const int* __restrict__ hi, __bf16* __restrict__ pooled) {
  int g = blockIdx.x;
  int l = lo[g], h = hi[g];
  int f = threadIdx.x;
  if (f >= HID) {
    int pad = f - HID;
    if (pad < KP_P - 2 * HID)
      pooled[(size_t)g * KP_P + 2 * HID + pad] = (__bf16)0.f;
    return;
  }
  float s = 0.f, mx = -1e30f;
  for (int n = l; n < h; n++) {
    float v = (float)out2[(size_t)n * LD_H + f];
    s += v;
    mx = fmaxf(mx, v);
  }
  if (h <= l) { s = 0.f; mx = 0.f; }
  else s = s / (float)(h - l);
  pooled[(size_t)g * KP_P + f] = (__bf16)s;
  pooled[(size_t)g * KP_P + HID + f] = (__bf16)mx;
}

// ---------------------------------------------------------------- launch
extern "C" void kernel_launch(void* const* d_in, const int* in_sizes, int n_in,
                              void* d_out, int out_size, void* d_ws,
                              size_t ws_size, hipStream_t stream) {
  const float* x        = (const float*)d_in[0];
  const int*   edge_idx = (const int*)d_in[1];
  const int*   batch    = (const int*)d_in[2];
  const float* W_gat    = (const float*)d_in[3];
  const float* att_src  = (const float*)d_in[4];
  const float* att_dst  = (const float*)d_in[5];
  const float* b_gat    = (const float*)d_in[6];
  const float* W_gcn    = (const float*)d_in[7];
  const float* b_gcn    = (const float*)d_in[8];
  const float* W1       = (const float*)d_in[9];
  const float* b1       = (const float*)d_in[10];
  const float* W2       = (const float*)d_in[11];
  const float* b2       = (const float*)d_in[12];
  float* out = (float*)d_out;
  (void)in_sizes; (void)n_in; (void)out_size; (void)ws_size;

  char* ws = (char*)d_ws;
  size_t off = 0;
  auto alloc = [&](size_t bytes) -> void* {
    void* p = ws + off;
    off += (bytes + 255) & ~(size_t)255;
    return p;
  };
  // bufR: A_bf [MP_N][KP_GCN] (dead after GEMM_B), then out2 bf16 [NN][LD_H]
  char*  bufR     = (char*)alloc((size_t)MP_N * KP_GCN * 2);      // 48.1 MB
  __bf16* A_bf    = (__bf16*)bufR;
  __bf16* out2b   = (__bf16*)bufR;
  __bf16* h_bf    = (__bf16*)alloc((size_t)MP_N * LD_H * 2);      // 47.2 MB
  __bf16* h2_bf   = (__bf16*)alloc((size_t)MP_N * LD_H * 2);      // 47.2 MB
  __bf16* x_bf    = (__bf16*)alloc((size_t)MP_N * KP_X * 2);      // 5.8 MB
  __bf16* WgatT   = (__bf16*)alloc((size_t)NP_HID * KP_X * 2);
  __bf16* WgcnT   = (__bf16*)alloc((size_t)NP_HID * KP_GCN * 2);
  __bf16* W1T     = (__bf16*)alloc((size_t)NP_W1 * KP_P * 2);
  __bf16* W2T     = (__bf16*)alloc((size_t)128 * LD_FC * 2);
  __bf16* pooled  = (__bf16*)alloc((size_t)MP_G * KP_P * 2);
  __bf16* hidfc   = (__bf16*)alloc((size_t)MP_G * LD_FC * 2);
  float* wsd      = (float*)alloc((size_t)FF * 2 * NH * 4);
  float* a_src_b  = (float*)alloc((size_t)NN * NH * 4);
  float* a_dst_b  = (float*)alloc((size_t)NN * NH * 4);
  float* p_csr    = (float*)alloc((size_t)ET * NH * 4);           // 10.8 MB
  int*   cnt      = (int*)alloc((size_t)NN * 4);
  int*   fill     = (int*)alloc((size_t)NN * 4);
  int*   row_ptr  = (int*)alloc((size_t)(NN + 1) * 4);
  int*   col_src  = (int*)alloc((size_t)ET * 4);
  int*   partial  = (int*)alloc((size_t)NBLK * 4);
  int*   offs     = (int*)alloc((size_t)NBLK * 4);
  int*   lo       = (int*)alloc((size_t)GG * 4);
  int*   hi       = (int*)alloc((size_t)GG * 4);
  float* dinv     = (float*)alloc((size_t)NN * 4);

  init_kernel<<<(NN + 255) / 256, 256, 0, stream>>>(cnt, fill, lo, hi);

  // one-time conversions
  xconv_kernel<<<(MP_N * KP_X + 255) / 256, 256, 0, stream>>>(x, x_bf);
  wconvT_kernel<<<(NP_HID * KP_X + 255) / 256, 256, 0, stream>>>(
      W_gat, WgatT, FF, HID, KP_X, NP_HID);
  wconvT_kernel<<<(NP_HID * KP_GCN + 255) / 256, 256, 0, stream>>>(
      W_gcn, WgcnT, HID, HID, KP_GCN, NP_HID);
  wconvT_kernel<<<(NP_W1 * KP_P + 255) / 256, 256, 0, stream>>>(
      W1, W1T, 2 * HID, 1500, KP_P, NP_W1);
  wconvT_kernel<<<(128 * LD_FC + 255) / 256, 256, 0, stream>>>(
      W2, W2T, 1500, 128, LD_FC, 128);
  wsd_kernel<<<(FF * 2 * NH + 255) / 256, 256, 0, stream>>>(
      W_gat, att_src, att_dst, wsd);

  {  // GEMM_A: h_bf = x @ W_gat
    dim3 grid(NP_HID / NT, MP_N / MT);
    mfma_gemm<true><<<grid, 256, 0, stream>>>(x_bf, WgatT, nullptr, h_bf,
                                              nullptr, NN, KP_X, HID, LD_H, 0,
                                              0, 0, 0);
  }
  adot_kernel<<<(NN * 2 * NH + 255) / 256, 256, 0, stream>>>(x, wsd, a_src_b,
                                                             a_dst_b);

  count_kernel<<<(ET + 255) / 256, 256, 0, stream>>>(edge_idx, batch, cnt, lo,
                                                     hi);
  scan1_kernel<<<NBLK, 1024, 0, stream>>>(cnt, row_ptr, partial);
  scan2_kernel<<<1, 64, 0, stream>>>(partial, offs);
  scan3_kernel<<<(NN + 255) / 256, 256, 0, stream>>>(row_ptr, offs, cnt, dinv);
  scatter_kernel<<<(ET + 255) / 256, 256, 0, stream>>>(
      edge_idx, row_ptr, fill, a_src_b, a_dst_b, col_src, p_csr);

  gat_aggr_kernel<<<NN, 128, 0, stream>>>(row_ptr, col_src, p_csr, h_bf,
                                          b_gat, A_bf);
  {  // GEMM_B: XCD-partitioned swizzle — 8 partitions x 30 row-tiles x 7 cols
    mfma_gemm<true><<<dim3(8 * 30 * 7), 256, 0, stream>>>(
        A_bf, WgcnT, nullptr, h2_bf, nullptr, NN, KP_GCN, HID, LD_H, 0,
        30, 7, MP_N / MT);
  }
  gcn_aggr_kernel<<<NN, 128, 0, stream>>>(row_ptr, col_src, dinv, h2_bf,
                                          b_gcn, out2b);

  pool_kernel<<<GG, 832, 0, stream>>>(out2b, lo, hi, pooled);

  {  // GEMM_C: hidfc = relu(pooled @ W1 + b1)
    dim3 grid(NP_W1 / NT, MP_G / MT);
    mfma_gemm<true><<<grid, 256, 0, stream>>>(pooled, W1T, nullptr, hidfc, b1,
                                              GG, KP_P, 1500, LD_FC, 1,
                                              0, 0, 0);
  }
  {  // GEMM_D: out = hidfc @ W2 + b2  (fp32 out)
    dim3 grid(1, MP_G / MT);
    mfma_gemm<false><<<grid, 256, 0, stream>>>(hidfc, W2T, out, nullptr, b2,
                                               GG, LD_FC, 128, 128, 0,
                                               0, 0, 0);
  }
}